// Round 7
// baseline (523.395 us; speedup 1.0000x reference)
//
#include <hip/hip_runtime.h>

// Batched ADMM QP solver. One block (256 thr, 4 waves) per batch.
// Setup: K = AtA + Q + sigma*I; register Gauss-Jordan; c = Kinv*p; d = -A*c;
//   P = A*Kinv*At in per-lane frags pacc[3][10] (8-lane group g: rows 3g..3g+2,
//   lane cc: cols 10cc..+9).
// Iterate up to 799x: s = P*w + d + y; z = clip(s,l,u); y = s-z; w = z-y.
// Round-7: bitwise fixed-point / period-2-cycle early exit. At it%4==2 compare
//   wsel vs the double-buffer's 2-iter-old value; block-wide OR via LDS flag
//   ring; uniform break. Exited blocks are bitwise-identical to the full run
//   (parity of check iters matches final iter 798).
// Epilogue: x = Kinv*(At*w) - c.

#define ITERS 800
#define SIGMA 1e-6f
#define WAM  68     // amat row stride
#define MROW 96     // M half-buffer row stride
#define WROW 12     // padded w chunk stride (10 used + 2 pad)

__device__ __forceinline__ float dpp_add(float x, const int ctrl) {
    int yi;
    switch (ctrl) {
        case 0xB1:  yi = __builtin_amdgcn_update_dpp(0, __float_as_int(x), 0xB1,  0xF, 0xF, true); break;
        case 0x4E:  yi = __builtin_amdgcn_update_dpp(0, __float_as_int(x), 0x4E,  0xF, 0xF, true); break;
        default:    yi = __builtin_amdgcn_update_dpp(0, __float_as_int(x), 0x141, 0xF, 0xF, true); break;
    }
    return x + __int_as_float(yi);
}

__global__ __launch_bounds__(256, 4)
void admm_qp_kernel(const float* __restrict__ Q, const float* __restrict__ p,
                    const float* __restrict__ A, const float* __restrict__ bvec,
                    const float* __restrict__ G, const float* __restrict__ h,
                    float* __restrict__ out)
{
    __shared__ float amat[80 * WAM];
    __shared__ float mh[32 * MROW];
    __shared__ float fcol[64];
    __shared__ float prow[64];
    __shared__ float pvec[64];
    __shared__ float cvec[64];
    __shared__ float dvec[80];
    __shared__ __align__(16) float wbuf[2 * 8 * WROW];
    __shared__ unsigned int flags[8];

    const int b  = blockIdx.x;
    const int t  = threadIdx.x;
    const int i  = t >> 2, qc = t & 3;   // setup/epilogue mapping
    const int g  = t >> 3, cc = t & 7;   // iteration mapping

    const float* Ab = A + (size_t)b * 16 * 64;
    const float* Gb = G + (size_t)b * 64 * 64;
    const float* Qb = Q + (size_t)b * 64 * 64;

    // ---- stage Amat=[A;G], pvec; zero w buffers + flags ----
    for (int e = t; e < 80 * 16; e += 256) {
        int row = e >> 4, seg = e & 15;
        const float* src = (row < 16) ? (Ab + row * 64 + seg * 4)
                                      : (Gb + (row - 16) * 64 + seg * 4);
        *(float4*)&amat[row * WAM + seg * 4] = *(const float4*)src;
    }
    if (t < 64) pvec[t] = p[(size_t)b * 64 + t];
    if (t < 2 * 8 * WROW) wbuf[t] = 0.f;
    if (t < 8) flags[t] = 0u;
    __syncthreads();

    // ---- K = AtA + Q + sigma*I ----
    float ar[16];
#pragma unroll
    for (int c = 0; c < 16; ++c) ar[c] = 0.f;
    for (int k = 0; k < 80; ++k) {
        const float* rowk = &amat[k * WAM];
        float av = rowk[i];
#pragma unroll
        for (int c4 = 0; c4 < 4; ++c4) {
            float4 bv = *(const float4*)&rowk[qc * 16 + 4 * c4];
            ar[4*c4+0] += av * bv.x; ar[4*c4+1] += av * bv.y;
            ar[4*c4+2] += av * bv.z; ar[4*c4+3] += av * bv.w;
        }
    }
#pragma unroll
    for (int c4 = 0; c4 < 4; ++c4) {
        float4 qv = *(const float4*)&Qb[i * 64 + qc * 16 + 4 * c4];
        ar[4*c4+0] += qv.x; ar[4*c4+1] += qv.y; ar[4*c4+2] += qv.z; ar[4*c4+3] += qv.w;
    }
    if ((i >> 4) == qc) ar[i & 15] += SIGMA;

    // ---- register Gauss-Jordan (K SPD, no pivoting) ----
    for (int po = 0; po < 4; ++po) {
#pragma unroll
        for (int pi = 0; pi < 16; ++pi) {
            const int pv = po * 16 + pi;
            if (qc == po) fcol[i] = ar[pi];
            __syncthreads();
            float pr = 1.0f / fcol[pv];
            float f  = fcol[i];
            if (i == pv) {
                float sp[16];
#pragma unroll
                for (int c = 0; c < 16; ++c) sp[c] = ar[c] * pr;
                if (qc == po) sp[pi] = pr;
#pragma unroll
                for (int c4 = 0; c4 < 4; ++c4)
                    *(float4*)&prow[qc * 16 + 4 * c4] =
                        make_float4(sp[4*c4], sp[4*c4+1], sp[4*c4+2], sp[4*c4+3]);
            }
            __syncthreads();
            float sp[16];
#pragma unroll
            for (int c4 = 0; c4 < 4; ++c4) {
                float4 v = *(const float4*)&prow[qc * 16 + 4 * c4];
                sp[4*c4] = v.x; sp[4*c4+1] = v.y; sp[4*c4+2] = v.z; sp[4*c4+3] = v.w;
            }
            if (i == pv) {
#pragma unroll
                for (int c = 0; c < 16; ++c) ar[c] = sp[c];
            } else {
#pragma unroll
                for (int c = 0; c < 16; ++c) ar[c] -= f * sp[c];
                if (qc == po) ar[pi] = -f * pr;
            }
        }
    }

    // ---- c = Kinv*p ----
    float creg;
    {
        float cacc = 0.f;
#pragma unroll
        for (int c4 = 0; c4 < 4; ++c4) {
            float4 pv4 = *(const float4*)&pvec[qc * 16 + 4 * c4];
            cacc += ar[4*c4]*pv4.x + ar[4*c4+1]*pv4.y + ar[4*c4+2]*pv4.z + ar[4*c4+3]*pv4.w;
        }
        cacc = dpp_add(cacc, 0xB1);
        cacc = dpp_add(cacc, 0x4E);
        creg = cacc;
        if (qc == 0) cvec[i] = cacc;
    }
    __syncthreads();

    // ---- d = -A*c ----
    if (t < 80) {
        float acc = 0.f;
#pragma unroll
        for (int k4 = 0; k4 < 16; ++k4) {
            float4 avv = *(const float4*)&amat[t * WAM + 4 * k4];
            float4 cv4 = *(const float4*)&cvec[4 * k4];
            acc += avv.x*cv4.x + avv.y*cv4.y + avv.z*cv4.z + avv.w*cv4.w;
        }
        dvec[t] = -acc;
    }
    __syncthreads();

    // ---- per-lane row state ----
    int rr[3];
    float dR[3], lR[3], uR[3], dyR[3];
#pragma unroll
    for (int j = 0; j < 3; ++j) {
        int r = 3 * g + j; if (r > 79) r = 79;
        rr[j] = r;
        dR[j] = dvec[r];
        if (r < 16) { float bb = bvec[(size_t)b * 16 + r]; lR[j] = bb; uR[j] = bb; }
        else        { lR[j] = -1e8f; uR[j] = h[(size_t)b * 64 + (r - 16)]; }
        dyR[j] = dR[j];
    }

    // ---- P = A*(Kinv*At): two k-passes ----
    float pacc[3][10];
#pragma unroll
    for (int j = 0; j < 3; ++j)
#pragma unroll
        for (int c = 0; c < 10; ++c) pacc[j][c] = 0.f;

    for (int ps = 0; ps < 2; ++ps) {
        if ((t >> 7) == ps) {
            const int mrow = i & 31;
            for (int jo = 0; jo < 8; ++jo) {
#pragma unroll
                for (int ji = 0; ji < 10; ++ji) {
                    const int j = jo * 10 + ji;
                    const float* rj = &amat[j * WAM + qc * 16];
                    float acc = 0.f;
#pragma unroll
                    for (int c4 = 0; c4 < 4; ++c4) {
                        float4 av = *(const float4*)&rj[4 * c4];
                        acc += ar[4*c4]*av.x + ar[4*c4+1]*av.y + ar[4*c4+2]*av.z + ar[4*c4+3]*av.w;
                    }
                    acc = dpp_add(acc, 0xB1);
                    acc = dpp_add(acc, 0x4E);
                    if (qc == (ji & 3)) mh[mrow * MROW + jo * WROW + ji] = acc;
                }
            }
        }
        __syncthreads();
#pragma unroll 2
        for (int kb = 0; kb < 8; ++kb) {
            float a0[4], a1[4], a2[4];
            { float4 v = *(const float4*)&amat[rr[0]*WAM + ps*32 + kb*4]; a0[0]=v.x;a0[1]=v.y;a0[2]=v.z;a0[3]=v.w; }
            { float4 v = *(const float4*)&amat[rr[1]*WAM + ps*32 + kb*4]; a1[0]=v.x;a1[1]=v.y;a1[2]=v.z;a1[3]=v.w; }
            { float4 v = *(const float4*)&amat[rr[2]*WAM + ps*32 + kb*4]; a2[0]=v.x;a2[1]=v.y;a2[2]=v.z;a2[3]=v.w; }
#pragma unroll
            for (int kk = 0; kk < 4; ++kk) {
                const float* mrp = &mh[(kb * 4 + kk) * MROW + cc * WROW];
                float4 ma = *(const float4*)&mrp[0];
                float4 mb = *(const float4*)&mrp[4];
                float2 mc = *(const float2*)&mrp[8];
                float m[10] = {ma.x, ma.y, ma.z, ma.w, mb.x, mb.y, mb.z, mb.w, mc.x, mc.y};
#pragma unroll
                for (int c = 0; c < 10; ++c) {
                    pacc[0][c] += a0[kk] * m[c];
                    pacc[1][c] += a1[kk] * m[c];
                    pacc[2][c] += a2[kk] * m[c];
                }
            }
        }
        __syncthreads();
    }

    // ---- iterations with bitwise fixed-point early exit ----
    const int wrow  = 3 * g + cc;
    const bool wvalid = (cc < 3) && (wrow < 80);
    const int widx  = (wrow < 80) ? ((wrow / 10) * WROW + (wrow % 10)) : 0;

#define DOT10(acc, row) \
    acc = pacc[row][0]*v04.x + pacc[row][1]*v04.y + pacc[row][2]*v04.z + pacc[row][3]*v04.w \
        + pacc[row][4]*v47.x + pacc[row][5]*v47.y + pacc[row][6]*v47.z + pacc[row][7]*v47.w \
        + pacc[row][8]*v89.x + pacc[row][9]*v89.y;
#define RED8(a) a = dpp_add(a, 0xB1); a = dpp_add(a, 0x4E); a = dpp_add(a, 0x141);
#define UPD(j, aj, wj) \
    { float s = aj + dyR[j]; float z = fminf(fmaxf(s, lR[j]), uR[j]); \
      float yn = s - z; dyR[j] = dR[j] + yn; wj = z - yn; }

    float* wc = wbuf;
    float* wn = wbuf + 8 * WROW;
    for (int it = 0; it < ITERS - 1; ++it) {
        const float* wp = wc + cc * WROW;
        float4 v04 = *(const float4*)&wp[0];
        float4 v47 = *(const float4*)&wp[4];
        float2 v89 = *(const float2*)&wp[8];
        float a0, a1, a2;
        DOT10(a0, 0) DOT10(a1, 1) DOT10(a2, 2)
        RED8(a0) RED8(a1) RED8(a2)
        float w0, w1, w2;
        UPD(0, a0, w0) UPD(1, a1, w1) UPD(2, a2, w2)
        float wsel = (cc == 1) ? w1 : ((cc == 2) ? w2 : w0);

        const bool chk = ((it & 3) == 2);     // it even: parity matches final it=798
        const int slot = (it >> 2) & 7;
        float oldw = 0.f;
        if (chk && wvalid) oldw = wn[widx];   // w from 2 iterations ago
        if (wvalid) wn[widx] = wsel;
        if (chk) {
            if (t == 0) flags[(slot + 1) & 7] = 0u;   // zero-ahead (28-iter separation)
            if (wvalid && wsel != oldw) flags[slot] = 1u;
        }
        __syncthreads();
        float* tmp = wc; wc = wn; wn = tmp;
        if (chk && flags[slot] == 0u) break;  // uniform: w in exact period<=2 cycle
    }

    // ---- epilogue: x = Kinv*(At*w_final) - c ----
    if (t < 64) {
        float acc = 0.f;
        for (int jo = 0; jo < 8; ++jo) {
#pragma unroll
            for (int ji = 0; ji < 10; ++ji)
                acc += amat[(jo * 10 + ji) * WAM + t] * wc[jo * WROW + ji];
        }
        fcol[t] = acc;
    }
    __syncthreads();
    float xp = 0.f;
#pragma unroll
    for (int c4 = 0; c4 < 4; ++c4) {
        float4 fv = *(const float4*)&fcol[qc * 16 + 4 * c4];
        xp += ar[4*c4]*fv.x + ar[4*c4+1]*fv.y + ar[4*c4+2]*fv.z + ar[4*c4+3]*fv.w;
    }
    xp = dpp_add(xp, 0xB1);
    xp = dpp_add(xp, 0x4E);
    if (qc == 0) out[(size_t)b * 64 + i] = xp - creg;
}

extern "C" void kernel_launch(void* const* d_in, const int* in_sizes, int n_in,
                              void* d_out, int out_size, void* d_ws, size_t ws_size,
                              hipStream_t stream) {
    const float* Q    = (const float*)d_in[0];
    const float* p    = (const float*)d_in[1];
    const float* A    = (const float*)d_in[2];
    const float* bvec = (const float*)d_in[3];
    const float* G    = (const float*)d_in[4];
    const float* h    = (const float*)d_in[5];
    float* out = (float*)d_out;
    admm_qp_kernel<<<1024, 256, 0, stream>>>(Q, p, A, bvec, G, h, out);
}

// Round 9
// 210.661 us; speedup vs baseline: 2.4845x; 2.4845x over previous
//
#include <hip/hip_runtime.h>

// Batched ADMM QP solver. One block (256 thr, 4 waves) per batch.
// Setup: K = AtA + Q + sigma*I; register Gauss-Jordan; c = Kinv*p; d = -A*c;
//   P = A*Kinv*At in per-lane frags (8-lane group g: rows 3g..3g+2, lane cc:
//   cols 10cc..+9), packed into vf2 for v_pk_fma_f32.
// Iterate <=799x: s = P*w + dy; z = med3(s,l,u); t = s-z; dy = d+t; w = z-t.
//   One barrier/iter, 8-lane DPP reduce, double-buffered padded w.
//   Lazy convergence exit: every 8th iter compare wsel vs 8-iter-old register
//   copy; block-OR flag in LDS ring; flag tested one check LATE.
// Round-9 fix: dyR must be added AFTER the 8-lane reduction (it is replicated
//   per-lane; folding it into the accumulator init summed it 8x -> divergence).
// Epilogue: x = Kinv*(At*w) - c.

#define ITERS 800
#define SIGMA 1e-6f
#define WAM  68     // amat row stride
#define MROW 96     // M half-buffer row stride
#define WROW 12     // padded w chunk stride (10 used + 2 pad)
#define EPS  4e-6f

typedef float vf2 __attribute__((ext_vector_type(2)));
typedef float vf4 __attribute__((ext_vector_type(4)));

__device__ __forceinline__ float dpp_add(float x, const int ctrl) {
    int yi;
    switch (ctrl) {
        case 0xB1:  yi = __builtin_amdgcn_update_dpp(0, __float_as_int(x), 0xB1,  0xF, 0xF, true); break;
        case 0x4E:  yi = __builtin_amdgcn_update_dpp(0, __float_as_int(x), 0x4E,  0xF, 0xF, true); break;
        default:    yi = __builtin_amdgcn_update_dpp(0, __float_as_int(x), 0x141, 0xF, 0xF, true); break;
    }
    return x + __int_as_float(yi);
}

__global__ __launch_bounds__(256, 4)
void admm_qp_kernel(const float* __restrict__ Q, const float* __restrict__ p,
                    const float* __restrict__ A, const float* __restrict__ bvec,
                    const float* __restrict__ G, const float* __restrict__ h,
                    float* __restrict__ out)
{
    __shared__ float amat[80 * WAM];
    __shared__ float mh[32 * MROW];
    __shared__ float fcol[64];
    __shared__ float prow[64];
    __shared__ float pvec[64];
    __shared__ float cvec[64];
    __shared__ float dvec[80];
    __shared__ __align__(16) float wbuf[2 * 8 * WROW];
    __shared__ unsigned int flagsL[4];

    const int b  = blockIdx.x;
    const int t  = threadIdx.x;
    const int i  = t >> 2, qc = t & 3;   // setup/epilogue mapping
    const int g  = t >> 3, cc = t & 7;   // iteration mapping

    const float* Ab = A + (size_t)b * 16 * 64;
    const float* Gb = G + (size_t)b * 64 * 64;
    const float* Qb = Q + (size_t)b * 64 * 64;

    // ---- stage Amat=[A;G], pvec; zero w buffers + flags ----
    for (int e = t; e < 80 * 16; e += 256) {
        int row = e >> 4, seg = e & 15;
        const float* src = (row < 16) ? (Ab + row * 64 + seg * 4)
                                      : (Gb + (row - 16) * 64 + seg * 4);
        *(float4*)&amat[row * WAM + seg * 4] = *(const float4*)src;
    }
    if (t < 64) pvec[t] = p[(size_t)b * 64 + t];
    if (t < 2 * 8 * WROW) wbuf[t] = 0.f;
    if (t < 4) flagsL[t] = 0u;
    __syncthreads();

    // ---- K = AtA + Q + sigma*I ----
    float ar[16];
#pragma unroll
    for (int c = 0; c < 16; ++c) ar[c] = 0.f;
    for (int k = 0; k < 80; ++k) {
        const float* rowk = &amat[k * WAM];
        float av = rowk[i];
#pragma unroll
        for (int c4 = 0; c4 < 4; ++c4) {
            float4 bv = *(const float4*)&rowk[qc * 16 + 4 * c4];
            ar[4*c4+0] += av * bv.x; ar[4*c4+1] += av * bv.y;
            ar[4*c4+2] += av * bv.z; ar[4*c4+3] += av * bv.w;
        }
    }
#pragma unroll
    for (int c4 = 0; c4 < 4; ++c4) {
        float4 qv = *(const float4*)&Qb[i * 64 + qc * 16 + 4 * c4];
        ar[4*c4+0] += qv.x; ar[4*c4+1] += qv.y; ar[4*c4+2] += qv.z; ar[4*c4+3] += qv.w;
    }
    if ((i >> 4) == qc) ar[i & 15] += SIGMA;

    // ---- register Gauss-Jordan (K SPD, no pivoting) ----
    for (int po = 0; po < 4; ++po) {
#pragma unroll
        for (int pi = 0; pi < 16; ++pi) {
            const int pv = po * 16 + pi;
            if (qc == po) fcol[i] = ar[pi];
            __syncthreads();
            float pr = 1.0f / fcol[pv];
            float f  = fcol[i];
            if (i == pv) {
                float sp[16];
#pragma unroll
                for (int c = 0; c < 16; ++c) sp[c] = ar[c] * pr;
                if (qc == po) sp[pi] = pr;
#pragma unroll
                for (int c4 = 0; c4 < 4; ++c4)
                    *(float4*)&prow[qc * 16 + 4 * c4] =
                        make_float4(sp[4*c4], sp[4*c4+1], sp[4*c4+2], sp[4*c4+3]);
            }
            __syncthreads();
            float sp[16];
#pragma unroll
            for (int c4 = 0; c4 < 4; ++c4) {
                float4 v = *(const float4*)&prow[qc * 16 + 4 * c4];
                sp[4*c4] = v.x; sp[4*c4+1] = v.y; sp[4*c4+2] = v.z; sp[4*c4+3] = v.w;
            }
            if (i == pv) {
#pragma unroll
                for (int c = 0; c < 16; ++c) ar[c] = sp[c];
            } else {
#pragma unroll
                for (int c = 0; c < 16; ++c) ar[c] -= f * sp[c];
                if (qc == po) ar[pi] = -f * pr;
            }
        }
    }

    // ---- c = Kinv*p ----
    float creg;
    {
        float cacc = 0.f;
#pragma unroll
        for (int c4 = 0; c4 < 4; ++c4) {
            float4 pv4 = *(const float4*)&pvec[qc * 16 + 4 * c4];
            cacc += ar[4*c4]*pv4.x + ar[4*c4+1]*pv4.y + ar[4*c4+2]*pv4.z + ar[4*c4+3]*pv4.w;
        }
        cacc = dpp_add(cacc, 0xB1);
        cacc = dpp_add(cacc, 0x4E);
        creg = cacc;
        if (qc == 0) cvec[i] = cacc;
    }
    __syncthreads();

    // ---- d = -A*c ----
    if (t < 80) {
        float acc = 0.f;
#pragma unroll
        for (int k4 = 0; k4 < 16; ++k4) {
            float4 avv = *(const float4*)&amat[t * WAM + 4 * k4];
            float4 cv4 = *(const float4*)&cvec[4 * k4];
            acc += avv.x*cv4.x + avv.y*cv4.y + avv.z*cv4.z + avv.w*cv4.w;
        }
        dvec[t] = -acc;
    }
    __syncthreads();

    // ---- per-lane row state ----
    int rr[3];
    float dR[3], lR[3], uR[3], dyR[3];
#pragma unroll
    for (int j = 0; j < 3; ++j) {
        int r = 3 * g + j; if (r > 79) r = 79;
        rr[j] = r;
        dR[j] = dvec[r];
        if (r < 16) { float bb = bvec[(size_t)b * 16 + r]; lR[j] = bb; uR[j] = bb; }
        else        { lR[j] = -1e8f; uR[j] = h[(size_t)b * 64 + (r - 16)]; }
        dyR[j] = dR[j];
    }

    // ---- P = A*(Kinv*At): two k-passes ----
    float pacc[3][10];
#pragma unroll
    for (int j = 0; j < 3; ++j)
#pragma unroll
        for (int c = 0; c < 10; ++c) pacc[j][c] = 0.f;

    for (int ps = 0; ps < 2; ++ps) {
        if ((t >> 7) == ps) {
            const int mrow = i & 31;
            for (int jo = 0; jo < 8; ++jo) {
#pragma unroll
                for (int ji = 0; ji < 10; ++ji) {
                    const int j = jo * 10 + ji;
                    const float* rj = &amat[j * WAM + qc * 16];
                    float acc = 0.f;
#pragma unroll
                    for (int c4 = 0; c4 < 4; ++c4) {
                        float4 av = *(const float4*)&rj[4 * c4];
                        acc += ar[4*c4]*av.x + ar[4*c4+1]*av.y + ar[4*c4+2]*av.z + ar[4*c4+3]*av.w;
                    }
                    acc = dpp_add(acc, 0xB1);
                    acc = dpp_add(acc, 0x4E);
                    if (qc == (ji & 3)) mh[mrow * MROW + jo * WROW + ji] = acc;
                }
            }
        }
        __syncthreads();
#pragma unroll 2
        for (int kb = 0; kb < 8; ++kb) {
            float a0[4], a1[4], a2[4];
            { float4 v = *(const float4*)&amat[rr[0]*WAM + ps*32 + kb*4]; a0[0]=v.x;a0[1]=v.y;a0[2]=v.z;a0[3]=v.w; }
            { float4 v = *(const float4*)&amat[rr[1]*WAM + ps*32 + kb*4]; a1[0]=v.x;a1[1]=v.y;a1[2]=v.z;a1[3]=v.w; }
            { float4 v = *(const float4*)&amat[rr[2]*WAM + ps*32 + kb*4]; a2[0]=v.x;a2[1]=v.y;a2[2]=v.z;a2[3]=v.w; }
#pragma unroll
            for (int kk = 0; kk < 4; ++kk) {
                const float* mrp = &mh[(kb * 4 + kk) * MROW + cc * WROW];
                float4 ma = *(const float4*)&mrp[0];
                float4 mb = *(const float4*)&mrp[4];
                float2 mc = *(const float2*)&mrp[8];
                float m[10] = {ma.x, ma.y, ma.z, ma.w, mb.x, mb.y, mb.z, mb.w, mc.x, mc.y};
#pragma unroll
                for (int c = 0; c < 10; ++c) {
                    pacc[0][c] += a0[kk] * m[c];
                    pacc[1][c] += a1[kk] * m[c];
                    pacc[2][c] += a2[kk] * m[c];
                }
            }
        }
        __syncthreads();
    }

    // ---- pack P fragments into vf2 pairs for v_pk_fma_f32 ----
    vf2 pk0[5], pk1[5], pk2[5];
#pragma unroll
    for (int c5 = 0; c5 < 5; ++c5) {
        pk0[c5] = (vf2){pacc[0][2*c5], pacc[0][2*c5+1]};
        pk1[c5] = (vf2){pacc[1][2*c5], pacc[1][2*c5+1]};
        pk2[c5] = (vf2){pacc[2][2*c5], pacc[2][2*c5+1]};
    }

    // ---- iterations ----
    const int wrow  = 3 * g + cc;
    const bool wvalid = (cc < 3) && (wrow < 80);
    const int widx  = (wrow < 80) ? ((wrow / 10) * WROW + (wrow % 10)) : 0;

#define RED8(a) a = dpp_add(a, 0xB1); a = dpp_add(a, 0x4E); a = dpp_add(a, 0x141);
#define UPD4(j, aj, wj) \
    { float s = aj + dyR[j]; float z = __builtin_amdgcn_fmed3f(s, lR[j], uR[j]); \
      float tt = s - z; dyR[j] = dR[j] + tt; wj = z - tt; }

    float wprev = 0.f;
    unsigned int fvreg = 1u;
    float* wc = wbuf;
    float* wn = wbuf + 8 * WROW;
    for (int it = 0; it < ITERS - 1; ++it) {
        const float* wp = wc + cc * WROW;
        vf4 v04 = *(const vf4*)&wp[0];
        vf4 v47 = *(const vf4*)&wp[4];
        vf2 v89 = *(const vf2*)&wp[8];
        vf2 wv0 = __builtin_shufflevector(v04, v04, 0, 1);
        vf2 wv1 = __builtin_shufflevector(v04, v04, 2, 3);
        vf2 wv2 = __builtin_shufflevector(v47, v47, 0, 1);
        vf2 wv3 = __builtin_shufflevector(v47, v47, 2, 3);
        vf2 A0 = {0.f, 0.f};           // dyR added AFTER reduction (replicated per-lane)
        vf2 A1 = {0.f, 0.f};
        vf2 A2 = {0.f, 0.f};
        asm("v_pk_fma_f32 %0, %1, %2, %0" : "+v"(A0) : "v"(pk0[0]), "v"(wv0));
        asm("v_pk_fma_f32 %0, %1, %2, %0" : "+v"(A1) : "v"(pk1[0]), "v"(wv0));
        asm("v_pk_fma_f32 %0, %1, %2, %0" : "+v"(A2) : "v"(pk2[0]), "v"(wv0));
        asm("v_pk_fma_f32 %0, %1, %2, %0" : "+v"(A0) : "v"(pk0[1]), "v"(wv1));
        asm("v_pk_fma_f32 %0, %1, %2, %0" : "+v"(A1) : "v"(pk1[1]), "v"(wv1));
        asm("v_pk_fma_f32 %0, %1, %2, %0" : "+v"(A2) : "v"(pk2[1]), "v"(wv1));
        asm("v_pk_fma_f32 %0, %1, %2, %0" : "+v"(A0) : "v"(pk0[2]), "v"(wv2));
        asm("v_pk_fma_f32 %0, %1, %2, %0" : "+v"(A1) : "v"(pk1[2]), "v"(wv2));
        asm("v_pk_fma_f32 %0, %1, %2, %0" : "+v"(A2) : "v"(pk2[2]), "v"(wv2));
        asm("v_pk_fma_f32 %0, %1, %2, %0" : "+v"(A0) : "v"(pk0[3]), "v"(wv3));
        asm("v_pk_fma_f32 %0, %1, %2, %0" : "+v"(A1) : "v"(pk1[3]), "v"(wv3));
        asm("v_pk_fma_f32 %0, %1, %2, %0" : "+v"(A2) : "v"(pk2[3]), "v"(wv3));
        asm("v_pk_fma_f32 %0, %1, %2, %0" : "+v"(A0) : "v"(pk0[4]), "v"(v89));
        asm("v_pk_fma_f32 %0, %1, %2, %0" : "+v"(A1) : "v"(pk1[4]), "v"(v89));
        asm("v_pk_fma_f32 %0, %1, %2, %0" : "+v"(A2) : "v"(pk2[4]), "v"(v89));
        float a0 = A0.x + A0.y, a1 = A1.x + A1.y, a2 = A2.x + A2.y;
        RED8(a0) RED8(a1) RED8(a2)
        float w0, w1, w2;
        UPD4(0, a0, w0) UPD4(1, a1, w1) UPD4(2, a2, w2)
        float wsel = (cc == 1) ? w1 : ((cc == 2) ? w2 : w0);
        if (wvalid) wn[widx] = wsel;

        const bool chk = ((it & 7) == 6);
        int slot = 0;
        if (chk) {
            slot = (it >> 3) & 3;
            if (wvalid && fabsf(wsel - wprev) > EPS) flagsL[slot] = 1u;
            if (t == 0) flagsL[(slot + 2) & 3] = 0u;
            wprev = wsel;
        }
        __syncthreads();
        float* tmp = wc; wc = wn; wn = tmp;
        if (chk) {
            if (fvreg == 0u) break;       // stale-by-8-iters convergence info
            fvreg = flagsL[slot];          // non-blocking: consumed next check
        }
    }

    // ---- epilogue: x = Kinv*(At*w_final) - c ----
    if (t < 64) {
        float acc = 0.f;
        for (int jo = 0; jo < 8; ++jo) {
#pragma unroll
            for (int ji = 0; ji < 10; ++ji)
                acc += amat[(jo * 10 + ji) * WAM + t] * wc[jo * WROW + ji];
        }
        fcol[t] = acc;
    }
    __syncthreads();
    float xp = 0.f;
#pragma unroll
    for (int c4 = 0; c4 < 4; ++c4) {
        float4 fv = *(const float4*)&fcol[qc * 16 + 4 * c4];
        xp += ar[4*c4]*fv.x + ar[4*c4+1]*fv.y + ar[4*c4+2]*fv.z + ar[4*c4+3]*fv.w;
    }
    xp = dpp_add(xp, 0xB1);
    xp = dpp_add(xp, 0x4E);
    if (qc == 0) out[(size_t)b * 64 + i] = xp - creg;
}

extern "C" void kernel_launch(void* const* d_in, const int* in_sizes, int n_in,
                              void* d_out, int out_size, void* d_ws, size_t ws_size,
                              hipStream_t stream) {
    const float* Q    = (const float*)d_in[0];
    const float* p    = (const float*)d_in[1];
    const float* A    = (const float*)d_in[2];
    const float* bvec = (const float*)d_in[3];
    const float* G    = (const float*)d_in[4];
    const float* h    = (const float*)d_in[5];
    float* out = (float*)d_out;
    admm_qp_kernel<<<1024, 256, 0, stream>>>(Q, p, A, bvec, G, h, out);
}

// Round 10
// 155.499 us; speedup vs baseline: 3.3659x; 1.3547x over previous
//
#include <hip/hip_runtime.h>

// Batched ADMM QP solver. One block (256 thr, 4 waves) per batch.
// Setup: K = AtA + Q + sigma*I; register Gauss-Jordan; c = Kinv*p; d = -A*c;
//   P = A*Kinv*At in per-lane frags (8-lane group g: rows 3g..3g+2, lane cc:
//   cols 10cc..+9), packed into vf2 for v_pk_fma_f32.
// Round-10: over-relaxed ADMM (alpha=1.6, OSQP-style). Same fixed point
//   (y-update forces Ax*=z*), ~1.3-2x fewer iterations. Per-row state now
//   {y, (1-alpha)z} instead of fused d+y. EPS 4e-6 -> 1e-5, check period
//   8 -> 4 (exit latency halved; zero-critical-path flag scheme of r9 kept).
// Iterate <=799x: ax = P*w + d; axr = a*ax + (1-a)z; s = axr + y;
//   z' = med3(s,l,u); y' = s - z'; w = z' - y'.
// Epilogue: x = Kinv*(At*w) - c.

#define ITERS 800
#define SIGMA 1e-6f
#define WAM  68     // amat row stride
#define MROW 96     // M half-buffer row stride
#define WROW 12     // padded w chunk stride (10 used + 2 pad)
#define EPS  1e-5f
#define ALPHA 1.6f
#define BETA  (-0.6f)   // 1 - ALPHA

typedef float vf2 __attribute__((ext_vector_type(2)));
typedef float vf4 __attribute__((ext_vector_type(4)));

__device__ __forceinline__ float dpp_add(float x, const int ctrl) {
    int yi;
    switch (ctrl) {
        case 0xB1:  yi = __builtin_amdgcn_update_dpp(0, __float_as_int(x), 0xB1,  0xF, 0xF, true); break;
        case 0x4E:  yi = __builtin_amdgcn_update_dpp(0, __float_as_int(x), 0x4E,  0xF, 0xF, true); break;
        default:    yi = __builtin_amdgcn_update_dpp(0, __float_as_int(x), 0x141, 0xF, 0xF, true); break;
    }
    return x + __int_as_float(yi);
}

__global__ __launch_bounds__(256, 4)
void admm_qp_kernel(const float* __restrict__ Q, const float* __restrict__ p,
                    const float* __restrict__ A, const float* __restrict__ bvec,
                    const float* __restrict__ G, const float* __restrict__ h,
                    float* __restrict__ out)
{
    __shared__ float amat[80 * WAM];
    __shared__ float mh[32 * MROW];
    __shared__ float fcol[64];
    __shared__ float prow[64];
    __shared__ float pvec[64];
    __shared__ float cvec[64];
    __shared__ float dvec[80];
    __shared__ __align__(16) float wbuf[2 * 8 * WROW];
    __shared__ unsigned int flagsL[4];

    const int b  = blockIdx.x;
    const int t  = threadIdx.x;
    const int i  = t >> 2, qc = t & 3;   // setup/epilogue mapping
    const int g  = t >> 3, cc = t & 7;   // iteration mapping

    const float* Ab = A + (size_t)b * 16 * 64;
    const float* Gb = G + (size_t)b * 64 * 64;
    const float* Qb = Q + (size_t)b * 64 * 64;

    // ---- stage Amat=[A;G], pvec; zero w buffers + flags ----
    for (int e = t; e < 80 * 16; e += 256) {
        int row = e >> 4, seg = e & 15;
        const float* src = (row < 16) ? (Ab + row * 64 + seg * 4)
                                      : (Gb + (row - 16) * 64 + seg * 4);
        *(float4*)&amat[row * WAM + seg * 4] = *(const float4*)src;
    }
    if (t < 64) pvec[t] = p[(size_t)b * 64 + t];
    if (t < 2 * 8 * WROW) wbuf[t] = 0.f;
    if (t < 4) flagsL[t] = 0u;
    __syncthreads();

    // ---- K = AtA + Q + sigma*I ----
    float ar[16];
#pragma unroll
    for (int c = 0; c < 16; ++c) ar[c] = 0.f;
    for (int k = 0; k < 80; ++k) {
        const float* rowk = &amat[k * WAM];
        float av = rowk[i];
#pragma unroll
        for (int c4 = 0; c4 < 4; ++c4) {
            float4 bv = *(const float4*)&rowk[qc * 16 + 4 * c4];
            ar[4*c4+0] += av * bv.x; ar[4*c4+1] += av * bv.y;
            ar[4*c4+2] += av * bv.z; ar[4*c4+3] += av * bv.w;
        }
    }
#pragma unroll
    for (int c4 = 0; c4 < 4; ++c4) {
        float4 qv = *(const float4*)&Qb[i * 64 + qc * 16 + 4 * c4];
        ar[4*c4+0] += qv.x; ar[4*c4+1] += qv.y; ar[4*c4+2] += qv.z; ar[4*c4+3] += qv.w;
    }
    if ((i >> 4) == qc) ar[i & 15] += SIGMA;

    // ---- register Gauss-Jordan (K SPD, no pivoting) ----
    for (int po = 0; po < 4; ++po) {
#pragma unroll
        for (int pi = 0; pi < 16; ++pi) {
            const int pv = po * 16 + pi;
            if (qc == po) fcol[i] = ar[pi];
            __syncthreads();
            float pr = 1.0f / fcol[pv];
            float f  = fcol[i];
            if (i == pv) {
                float sp[16];
#pragma unroll
                for (int c = 0; c < 16; ++c) sp[c] = ar[c] * pr;
                if (qc == po) sp[pi] = pr;
#pragma unroll
                for (int c4 = 0; c4 < 4; ++c4)
                    *(float4*)&prow[qc * 16 + 4 * c4] =
                        make_float4(sp[4*c4], sp[4*c4+1], sp[4*c4+2], sp[4*c4+3]);
            }
            __syncthreads();
            float sp[16];
#pragma unroll
            for (int c4 = 0; c4 < 4; ++c4) {
                float4 v = *(const float4*)&prow[qc * 16 + 4 * c4];
                sp[4*c4] = v.x; sp[4*c4+1] = v.y; sp[4*c4+2] = v.z; sp[4*c4+3] = v.w;
            }
            if (i == pv) {
#pragma unroll
                for (int c = 0; c < 16; ++c) ar[c] = sp[c];
            } else {
#pragma unroll
                for (int c = 0; c < 16; ++c) ar[c] -= f * sp[c];
                if (qc == po) ar[pi] = -f * pr;
            }
        }
    }

    // ---- c = Kinv*p ----
    float creg;
    {
        float cacc = 0.f;
#pragma unroll
        for (int c4 = 0; c4 < 4; ++c4) {
            float4 pv4 = *(const float4*)&pvec[qc * 16 + 4 * c4];
            cacc += ar[4*c4]*pv4.x + ar[4*c4+1]*pv4.y + ar[4*c4+2]*pv4.z + ar[4*c4+3]*pv4.w;
        }
        cacc = dpp_add(cacc, 0xB1);
        cacc = dpp_add(cacc, 0x4E);
        creg = cacc;
        if (qc == 0) cvec[i] = cacc;
    }
    __syncthreads();

    // ---- d = -A*c ----
    if (t < 80) {
        float acc = 0.f;
#pragma unroll
        for (int k4 = 0; k4 < 16; ++k4) {
            float4 avv = *(const float4*)&amat[t * WAM + 4 * k4];
            float4 cv4 = *(const float4*)&cvec[4 * k4];
            acc += avv.x*cv4.x + avv.y*cv4.y + avv.z*cv4.z + avv.w*cv4.w;
        }
        dvec[t] = -acc;
    }
    __syncthreads();

    // ---- per-lane row state ----
    int rr[3];
    float dR[3], lR[3], uR[3], yR[3], zmR[3];
#pragma unroll
    for (int j = 0; j < 3; ++j) {
        int r = 3 * g + j; if (r > 79) r = 79;
        rr[j] = r;
        dR[j] = dvec[r];
        if (r < 16) { float bb = bvec[(size_t)b * 16 + r]; lR[j] = bb; uR[j] = bb; }
        else        { lR[j] = -1e8f; uR[j] = h[(size_t)b * 64 + (r - 16)]; }
        yR[j] = 0.f; zmR[j] = 0.f;     // y0 = 0, z0 = 0
    }

    // ---- P = A*(Kinv*At): two k-passes ----
    float pacc[3][10];
#pragma unroll
    for (int j = 0; j < 3; ++j)
#pragma unroll
        for (int c = 0; c < 10; ++c) pacc[j][c] = 0.f;

    for (int ps = 0; ps < 2; ++ps) {
        if ((t >> 7) == ps) {
            const int mrow = i & 31;
            for (int jo = 0; jo < 8; ++jo) {
#pragma unroll
                for (int ji = 0; ji < 10; ++ji) {
                    const int j = jo * 10 + ji;
                    const float* rj = &amat[j * WAM + qc * 16];
                    float acc = 0.f;
#pragma unroll
                    for (int c4 = 0; c4 < 4; ++c4) {
                        float4 av = *(const float4*)&rj[4 * c4];
                        acc += ar[4*c4]*av.x + ar[4*c4+1]*av.y + ar[4*c4+2]*av.z + ar[4*c4+3]*av.w;
                    }
                    acc = dpp_add(acc, 0xB1);
                    acc = dpp_add(acc, 0x4E);
                    if (qc == (ji & 3)) mh[mrow * MROW + jo * WROW + ji] = acc;
                }
            }
        }
        __syncthreads();
#pragma unroll 2
        for (int kb = 0; kb < 8; ++kb) {
            float a0[4], a1[4], a2[4];
            { float4 v = *(const float4*)&amat[rr[0]*WAM + ps*32 + kb*4]; a0[0]=v.x;a0[1]=v.y;a0[2]=v.z;a0[3]=v.w; }
            { float4 v = *(const float4*)&amat[rr[1]*WAM + ps*32 + kb*4]; a1[0]=v.x;a1[1]=v.y;a1[2]=v.z;a1[3]=v.w; }
            { float4 v = *(const float4*)&amat[rr[2]*WAM + ps*32 + kb*4]; a2[0]=v.x;a2[1]=v.y;a2[2]=v.z;a2[3]=v.w; }
#pragma unroll
            for (int kk = 0; kk < 4; ++kk) {
                const float* mrp = &mh[(kb * 4 + kk) * MROW + cc * WROW];
                float4 ma = *(const float4*)&mrp[0];
                float4 mb = *(const float4*)&mrp[4];
                float2 mc = *(const float2*)&mrp[8];
                float m[10] = {ma.x, ma.y, ma.z, ma.w, mb.x, mb.y, mb.z, mb.w, mc.x, mc.y};
#pragma unroll
                for (int c = 0; c < 10; ++c) {
                    pacc[0][c] += a0[kk] * m[c];
                    pacc[1][c] += a1[kk] * m[c];
                    pacc[2][c] += a2[kk] * m[c];
                }
            }
        }
        __syncthreads();
    }

    // ---- pack P fragments into vf2 pairs for v_pk_fma_f32 ----
    vf2 pk0[5], pk1[5], pk2[5];
#pragma unroll
    for (int c5 = 0; c5 < 5; ++c5) {
        pk0[c5] = (vf2){pacc[0][2*c5], pacc[0][2*c5+1]};
        pk1[c5] = (vf2){pacc[1][2*c5], pacc[1][2*c5+1]};
        pk2[c5] = (vf2){pacc[2][2*c5], pacc[2][2*c5+1]};
    }

    // ---- iterations (over-relaxed) ----
    const int wrow  = 3 * g + cc;
    const bool wvalid = (cc < 3) && (wrow < 80);
    const int widx  = (wrow < 80) ? ((wrow / 10) * WROW + (wrow % 10)) : 0;

#define RED8(a) a = dpp_add(a, 0xB1); a = dpp_add(a, 0x4E); a = dpp_add(a, 0x141);
#define UPD5(j, aj, wj) \
    { float ax = aj + dR[j]; \
      float axr = ALPHA * ax + zmR[j]; \
      float s = axr + yR[j]; \
      float z = __builtin_amdgcn_fmed3f(s, lR[j], uR[j]); \
      yR[j] = s - z; zmR[j] = BETA * z; wj = z - yR[j]; }

    float wprev = 0.f;
    unsigned int fvreg = 1u;
    float* wc = wbuf;
    float* wn = wbuf + 8 * WROW;
    for (int it = 0; it < ITERS - 1; ++it) {
        const float* wp = wc + cc * WROW;
        vf4 v04 = *(const vf4*)&wp[0];
        vf4 v47 = *(const vf4*)&wp[4];
        vf2 v89 = *(const vf2*)&wp[8];
        vf2 wv0 = __builtin_shufflevector(v04, v04, 0, 1);
        vf2 wv1 = __builtin_shufflevector(v04, v04, 2, 3);
        vf2 wv2 = __builtin_shufflevector(v47, v47, 0, 1);
        vf2 wv3 = __builtin_shufflevector(v47, v47, 2, 3);
        vf2 A0 = {0.f, 0.f};
        vf2 A1 = {0.f, 0.f};
        vf2 A2 = {0.f, 0.f};
        asm("v_pk_fma_f32 %0, %1, %2, %0" : "+v"(A0) : "v"(pk0[0]), "v"(wv0));
        asm("v_pk_fma_f32 %0, %1, %2, %0" : "+v"(A1) : "v"(pk1[0]), "v"(wv0));
        asm("v_pk_fma_f32 %0, %1, %2, %0" : "+v"(A2) : "v"(pk2[0]), "v"(wv0));
        asm("v_pk_fma_f32 %0, %1, %2, %0" : "+v"(A0) : "v"(pk0[1]), "v"(wv1));
        asm("v_pk_fma_f32 %0, %1, %2, %0" : "+v"(A1) : "v"(pk1[1]), "v"(wv1));
        asm("v_pk_fma_f32 %0, %1, %2, %0" : "+v"(A2) : "v"(pk2[1]), "v"(wv1));
        asm("v_pk_fma_f32 %0, %1, %2, %0" : "+v"(A0) : "v"(pk0[2]), "v"(wv2));
        asm("v_pk_fma_f32 %0, %1, %2, %0" : "+v"(A1) : "v"(pk1[2]), "v"(wv2));
        asm("v_pk_fma_f32 %0, %1, %2, %0" : "+v"(A2) : "v"(pk2[2]), "v"(wv2));
        asm("v_pk_fma_f32 %0, %1, %2, %0" : "+v"(A0) : "v"(pk0[3]), "v"(wv3));
        asm("v_pk_fma_f32 %0, %1, %2, %0" : "+v"(A1) : "v"(pk1[3]), "v"(wv3));
        asm("v_pk_fma_f32 %0, %1, %2, %0" : "+v"(A2) : "v"(pk2[3]), "v"(wv3));
        asm("v_pk_fma_f32 %0, %1, %2, %0" : "+v"(A0) : "v"(pk0[4]), "v"(v89));
        asm("v_pk_fma_f32 %0, %1, %2, %0" : "+v"(A1) : "v"(pk1[4]), "v"(v89));
        asm("v_pk_fma_f32 %0, %1, %2, %0" : "+v"(A2) : "v"(pk2[4]), "v"(v89));
        float a0 = A0.x + A0.y, a1 = A1.x + A1.y, a2 = A2.x + A2.y;
        RED8(a0) RED8(a1) RED8(a2)
        float w0, w1, w2;
        UPD5(0, a0, w0) UPD5(1, a1, w1) UPD5(2, a2, w2)
        float wsel = (cc == 1) ? w1 : ((cc == 2) ? w2 : w0);
        if (wvalid) wn[widx] = wsel;

        const bool chk = ((it & 3) == 3);
        int slot = 0;
        if (chk) {
            slot = (it >> 2) & 3;
            if (wvalid && fabsf(wsel - wprev) > EPS) flagsL[slot] = 1u;
            if (t == 0) flagsL[(slot + 2) & 3] = 0u;
            wprev = wsel;
        }
        __syncthreads();
        float* tmp = wc; wc = wn; wn = tmp;
        if (chk) {
            if (fvreg == 0u) break;       // stale-by-4-iters convergence info
            fvreg = flagsL[slot];          // non-blocking: consumed next check
        }
    }

    // ---- epilogue: x = Kinv*(At*w_final) - c ----
    if (t < 64) {
        float acc = 0.f;
        for (int jo = 0; jo < 8; ++jo) {
#pragma unroll
            for (int ji = 0; ji < 10; ++ji)
                acc += amat[(jo * 10 + ji) * WAM + t] * wc[jo * WROW + ji];
        }
        fcol[t] = acc;
    }
    __syncthreads();
    float xp = 0.f;
#pragma unroll
    for (int c4 = 0; c4 < 4; ++c4) {
        float4 fv = *(const float4*)&fcol[qc * 16 + 4 * c4];
        xp += ar[4*c4]*fv.x + ar[4*c4+1]*fv.y + ar[4*c4+2]*fv.z + ar[4*c4+3]*fv.w;
    }
    xp = dpp_add(xp, 0xB1);
    xp = dpp_add(xp, 0x4E);
    if (qc == 0) out[(size_t)b * 64 + i] = xp - creg;
}

extern "C" void kernel_launch(void* const* d_in, const int* in_sizes, int n_in,
                              void* d_out, int out_size, void* d_ws, size_t ws_size,
                              hipStream_t stream) {
    const float* Q    = (const float*)d_in[0];
    const float* p    = (const float*)d_in[1];
    const float* A    = (const float*)d_in[2];
    const float* bvec = (const float*)d_in[3];
    const float* G    = (const float*)d_in[4];
    const float* h    = (const float*)d_in[5];
    float* out = (float*)d_out;
    admm_qp_kernel<<<1024, 256, 0, stream>>>(Q, p, A, bvec, G, h, out);
}

// Round 11
// 130.076 us; speedup vs baseline: 4.0238x; 1.1954x over previous
//
#include <hip/hip_runtime.h>

// Batched ADMM QP solver. One block (256 thr, 4 waves) per batch.
// Setup: K = AtA + Q + sigma*I; BLOCKED-2 register Gauss-Jordan (exact 2x2
//   block jordan-exchange, 64 barriers instead of 128); c = Kinv*p; d = -A*c;
//   P = A*Kinv*At in per-lane frags, packed vf2 for v_pk_fma_f32.
// Iterate <=800x (unrolled x2, static double buffers): over-relaxed ADMM
//   alpha=1.6: ax = P*w + d; axr = a*ax + (1-a)z; s = axr + y; z' = med3(s,l,u);
//   y' = s - z'; w = z' - y'. Lazy zero-critical-path convergence exit
//   (check every 4th iter, flag ring, tested one check late), EPS=1e-4.
// Epilogue: x = Kinv*(At*w) - c.

#define ITERS 800
#define SIGMA 1e-6f
#define WAM  68     // amat row stride
#define MROW 96     // M half-buffer row stride
#define WROW 12     // padded w chunk stride (10 used + 2 pad)
#define EPS  1e-4f
#define ALPHA 1.6f
#define BETA  (-0.6f)   // 1 - ALPHA

typedef float vf2 __attribute__((ext_vector_type(2)));
typedef float vf4 __attribute__((ext_vector_type(4)));

__device__ __forceinline__ float dpp_add(float x, const int ctrl) {
    int yi;
    switch (ctrl) {
        case 0xB1:  yi = __builtin_amdgcn_update_dpp(0, __float_as_int(x), 0xB1,  0xF, 0xF, true); break;
        case 0x4E:  yi = __builtin_amdgcn_update_dpp(0, __float_as_int(x), 0x4E,  0xF, 0xF, true); break;
        default:    yi = __builtin_amdgcn_update_dpp(0, __float_as_int(x), 0x141, 0xF, 0xF, true); break;
    }
    return x + __int_as_float(yi);
}

__global__ __launch_bounds__(256, 4)
void admm_qp_kernel(const float* __restrict__ Q, const float* __restrict__ p,
                    const float* __restrict__ A, const float* __restrict__ bvec,
                    const float* __restrict__ G, const float* __restrict__ h,
                    float* __restrict__ out)
{
    __shared__ float amat[80 * WAM];
    __shared__ float mh[32 * MROW];
    __shared__ float fcol[64];
    __shared__ float2 fcolB[64];       // raw (K[i][c0], K[i][c1]) for blocked GJ
    __shared__ float prow2[2 * 64];    // raw pivot rows p0, p1
    __shared__ float pvec[64];
    __shared__ float cvec[64];
    __shared__ float dvec[80];
    __shared__ __align__(16) float wbuf[2 * 8 * WROW];
    __shared__ unsigned int flagsL[4];

    const int b  = blockIdx.x;
    const int t  = threadIdx.x;
    const int i  = t >> 2, qc = t & 3;   // setup/epilogue mapping
    const int g  = t >> 3, cc = t & 7;   // iteration mapping

    const float* Ab = A + (size_t)b * 16 * 64;
    const float* Gb = G + (size_t)b * 64 * 64;
    const float* Qb = Q + (size_t)b * 64 * 64;

    // ---- stage Amat=[A;G], pvec; zero w buffers + flags ----
    for (int e = t; e < 80 * 16; e += 256) {
        int row = e >> 4, seg = e & 15;
        const float* src = (row < 16) ? (Ab + row * 64 + seg * 4)
                                      : (Gb + (row - 16) * 64 + seg * 4);
        *(float4*)&amat[row * WAM + seg * 4] = *(const float4*)src;
    }
    if (t < 64) pvec[t] = p[(size_t)b * 64 + t];
    if (t < 2 * 8 * WROW) wbuf[t] = 0.f;
    if (t < 4) flagsL[t] = 0u;
    __syncthreads();

    // ---- K = AtA + Q + sigma*I ----
    float ar[16];
#pragma unroll
    for (int c = 0; c < 16; ++c) ar[c] = 0.f;
    for (int k = 0; k < 80; ++k) {
        const float* rowk = &amat[k * WAM];
        float av = rowk[i];
#pragma unroll
        for (int c4 = 0; c4 < 4; ++c4) {
            float4 bv = *(const float4*)&rowk[qc * 16 + 4 * c4];
            ar[4*c4+0] += av * bv.x; ar[4*c4+1] += av * bv.y;
            ar[4*c4+2] += av * bv.z; ar[4*c4+3] += av * bv.w;
        }
    }
#pragma unroll
    for (int c4 = 0; c4 < 4; ++c4) {
        float4 qv = *(const float4*)&Qb[i * 64 + qc * 16 + 4 * c4];
        ar[4*c4+0] += qv.x; ar[4*c4+1] += qv.y; ar[4*c4+2] += qv.z; ar[4*c4+3] += qv.w;
    }
    if ((i >> 4) == qc) ar[i & 15] += SIGMA;

    // ---- BLOCKED-2 register Gauss-Jordan (K SPD, no pivoting) ----
    // Exact 2x2-block jordan exchange: per pair (p0,p1) publish raw fcol pair
    // + raw pivot rows once, then every thread applies Binv-based update.
    for (int po = 0; po < 4; ++po) {
#pragma unroll
        for (int kbi = 0; kbi < 8; ++kbi) {
            const int p0 = po * 16 + 2 * kbi;
            const int p1 = p0 + 1;
            const int c0 = 2 * kbi;           // static
            const int c1 = c0 + 1;            // static
            if (qc == po) fcolB[i] = make_float2(ar[c0], ar[c1]);
            if (i == p0) {
#pragma unroll
                for (int c4 = 0; c4 < 4; ++c4)
                    *(float4*)&prow2[qc * 16 + 4 * c4] =
                        make_float4(ar[4*c4], ar[4*c4+1], ar[4*c4+2], ar[4*c4+3]);
            }
            if (i == p1) {
#pragma unroll
                for (int c4 = 0; c4 < 4; ++c4)
                    *(float4*)&prow2[64 + qc * 16 + 4 * c4] =
                        make_float4(ar[4*c4], ar[4*c4+1], ar[4*c4+2], ar[4*c4+3]);
            }
            __syncthreads();
            float2 fb = fcolB[i];
            float2 r0 = fcolB[p0];            // (a00, a01)
            float2 r1 = fcolB[p1];            // (a10, a11)
            float dinv = 1.0f / (r0.x * r1.y - r0.y * r1.x);
            float b00 =  r1.y * dinv, b01 = -r0.y * dinv;
            float b10 = -r1.x * dinv, b11 =  r0.x * dinv;
            float sp0[16], sp1[16];
#pragma unroll
            for (int c4 = 0; c4 < 4; ++c4) {
                float4 v0 = *(const float4*)&prow2[qc * 16 + 4 * c4];
                float4 v1 = *(const float4*)&prow2[64 + qc * 16 + 4 * c4];
                sp0[4*c4] = v0.x; sp0[4*c4+1] = v0.y; sp0[4*c4+2] = v0.z; sp0[4*c4+3] = v0.w;
                sp1[4*c4] = v1.x; sp1[4*c4+1] = v1.y; sp1[4*c4+2] = v1.z; sp1[4*c4+3] = v1.w;
            }
            if (i == p0) {
#pragma unroll
                for (int c = 0; c < 16; ++c) ar[c] = b00 * sp0[c] + b01 * sp1[c];
                if (qc == po) { ar[c0] = b00; ar[c1] = b01; }
            } else if (i == p1) {
#pragma unroll
                for (int c = 0; c < 16; ++c) ar[c] = b10 * sp0[c] + b11 * sp1[c];
                if (qc == po) { ar[c0] = b10; ar[c1] = b11; }
            } else {
                float g0 = fb.x * b00 + fb.y * b10;
                float g1 = fb.x * b01 + fb.y * b11;
#pragma unroll
                for (int c = 0; c < 16; ++c) ar[c] -= g0 * sp0[c] + g1 * sp1[c];
                if (qc == po) { ar[c0] = -g0; ar[c1] = -g1; }
            }
            __syncthreads();
        }
    }

    // ---- c = Kinv*p ----
    float creg;
    {
        float cacc = 0.f;
#pragma unroll
        for (int c4 = 0; c4 < 4; ++c4) {
            float4 pv4 = *(const float4*)&pvec[qc * 16 + 4 * c4];
            cacc += ar[4*c4]*pv4.x + ar[4*c4+1]*pv4.y + ar[4*c4+2]*pv4.z + ar[4*c4+3]*pv4.w;
        }
        cacc = dpp_add(cacc, 0xB1);
        cacc = dpp_add(cacc, 0x4E);
        creg = cacc;
        if (qc == 0) cvec[i] = cacc;
    }
    __syncthreads();

    // ---- d = -A*c ----
    if (t < 80) {
        float acc = 0.f;
#pragma unroll
        for (int k4 = 0; k4 < 16; ++k4) {
            float4 avv = *(const float4*)&amat[t * WAM + 4 * k4];
            float4 cv4 = *(const float4*)&cvec[4 * k4];
            acc += avv.x*cv4.x + avv.y*cv4.y + avv.z*cv4.z + avv.w*cv4.w;
        }
        dvec[t] = -acc;
    }
    __syncthreads();

    // ---- per-lane row state ----
    int rr[3];
    float dR[3], lR[3], uR[3], yR[3], zmR[3];
#pragma unroll
    for (int j = 0; j < 3; ++j) {
        int r = 3 * g + j; if (r > 79) r = 79;
        rr[j] = r;
        dR[j] = dvec[r];
        if (r < 16) { float bb = bvec[(size_t)b * 16 + r]; lR[j] = bb; uR[j] = bb; }
        else        { lR[j] = -1e8f; uR[j] = h[(size_t)b * 64 + (r - 16)]; }
        yR[j] = 0.f; zmR[j] = 0.f;     // y0 = 0, z0 = 0
    }

    // ---- P = A*(Kinv*At): two k-passes ----
    float pacc[3][10];
#pragma unroll
    for (int j = 0; j < 3; ++j)
#pragma unroll
        for (int c = 0; c < 10; ++c) pacc[j][c] = 0.f;

    for (int ps = 0; ps < 2; ++ps) {
        if ((t >> 7) == ps) {
            const int mrow = i & 31;
            for (int jo = 0; jo < 8; ++jo) {
#pragma unroll
                for (int ji = 0; ji < 10; ++ji) {
                    const int j = jo * 10 + ji;
                    const float* rj = &amat[j * WAM + qc * 16];
                    float acc = 0.f;
#pragma unroll
                    for (int c4 = 0; c4 < 4; ++c4) {
                        float4 av = *(const float4*)&rj[4 * c4];
                        acc += ar[4*c4]*av.x + ar[4*c4+1]*av.y + ar[4*c4+2]*av.z + ar[4*c4+3]*av.w;
                    }
                    acc = dpp_add(acc, 0xB1);
                    acc = dpp_add(acc, 0x4E);
                    if (qc == (ji & 3)) mh[mrow * MROW + jo * WROW + ji] = acc;
                }
            }
        }
        __syncthreads();
#pragma unroll 2
        for (int kb = 0; kb < 8; ++kb) {
            float a0[4], a1[4], a2[4];
            { float4 v = *(const float4*)&amat[rr[0]*WAM + ps*32 + kb*4]; a0[0]=v.x;a0[1]=v.y;a0[2]=v.z;a0[3]=v.w; }
            { float4 v = *(const float4*)&amat[rr[1]*WAM + ps*32 + kb*4]; a1[0]=v.x;a1[1]=v.y;a1[2]=v.z;a1[3]=v.w; }
            { float4 v = *(const float4*)&amat[rr[2]*WAM + ps*32 + kb*4]; a2[0]=v.x;a2[1]=v.y;a2[2]=v.z;a2[3]=v.w; }
#pragma unroll
            for (int kk = 0; kk < 4; ++kk) {
                const float* mrp = &mh[(kb * 4 + kk) * MROW + cc * WROW];
                float4 ma = *(const float4*)&mrp[0];
                float4 mb = *(const float4*)&mrp[4];
                float2 mc = *(const float2*)&mrp[8];
                float m[10] = {ma.x, ma.y, ma.z, ma.w, mb.x, mb.y, mb.z, mb.w, mc.x, mc.y};
#pragma unroll
                for (int c = 0; c < 10; ++c) {
                    pacc[0][c] += a0[kk] * m[c];
                    pacc[1][c] += a1[kk] * m[c];
                    pacc[2][c] += a2[kk] * m[c];
                }
            }
        }
        __syncthreads();
    }

    // ---- pack P fragments into vf2 pairs for v_pk_fma_f32 ----
    vf2 pk0[5], pk1[5], pk2[5];
#pragma unroll
    for (int c5 = 0; c5 < 5; ++c5) {
        pk0[c5] = (vf2){pacc[0][2*c5], pacc[0][2*c5+1]};
        pk1[c5] = (vf2){pacc[1][2*c5], pacc[1][2*c5+1]};
        pk2[c5] = (vf2){pacc[2][2*c5], pacc[2][2*c5+1]};
    }

    // ---- iterations (over-relaxed), unrolled x2 with static buffers ----
    const int wrow  = 3 * g + cc;
    const bool wvalid = (cc < 3) && (wrow < 80);
    const int widx  = (wrow < 80) ? ((wrow / 10) * WROW + (wrow % 10)) : 0;

#define RED8(a) a = dpp_add(a, 0xB1); a = dpp_add(a, 0x4E); a = dpp_add(a, 0x141);
#define UPD5(j, aj, wj) \
    { float ax = aj + dR[j]; \
      float axr = ALPHA * ax + zmR[j]; \
      float s = axr + yR[j]; \
      float z = __builtin_amdgcn_fmed3f(s, lR[j], uR[j]); \
      yR[j] = s - z; zmR[j] = BETA * z; wj = z - yR[j]; }

#define ITERBODY(WCP, WNP) { \
    const float* wp = (WCP) + cc * WROW; \
    vf4 v04 = *(const vf4*)&wp[0]; \
    vf4 v47 = *(const vf4*)&wp[4]; \
    vf2 v89 = *(const vf2*)&wp[8]; \
    vf2 wv0 = __builtin_shufflevector(v04, v04, 0, 1); \
    vf2 wv1 = __builtin_shufflevector(v04, v04, 2, 3); \
    vf2 wv2 = __builtin_shufflevector(v47, v47, 0, 1); \
    vf2 wv3 = __builtin_shufflevector(v47, v47, 2, 3); \
    vf2 A0 = {0.f, 0.f}; vf2 A1 = {0.f, 0.f}; vf2 A2 = {0.f, 0.f}; \
    asm("v_pk_fma_f32 %0, %1, %2, %0" : "+v"(A0) : "v"(pk0[0]), "v"(wv0)); \
    asm("v_pk_fma_f32 %0, %1, %2, %0" : "+v"(A1) : "v"(pk1[0]), "v"(wv0)); \
    asm("v_pk_fma_f32 %0, %1, %2, %0" : "+v"(A2) : "v"(pk2[0]), "v"(wv0)); \
    asm("v_pk_fma_f32 %0, %1, %2, %0" : "+v"(A0) : "v"(pk0[1]), "v"(wv1)); \
    asm("v_pk_fma_f32 %0, %1, %2, %0" : "+v"(A1) : "v"(pk1[1]), "v"(wv1)); \
    asm("v_pk_fma_f32 %0, %1, %2, %0" : "+v"(A2) : "v"(pk2[1]), "v"(wv1)); \
    asm("v_pk_fma_f32 %0, %1, %2, %0" : "+v"(A0) : "v"(pk0[2]), "v"(wv2)); \
    asm("v_pk_fma_f32 %0, %1, %2, %0" : "+v"(A1) : "v"(pk1[2]), "v"(wv2)); \
    asm("v_pk_fma_f32 %0, %1, %2, %0" : "+v"(A2) : "v"(pk2[2]), "v"(wv2)); \
    asm("v_pk_fma_f32 %0, %1, %2, %0" : "+v"(A0) : "v"(pk0[3]), "v"(wv3)); \
    asm("v_pk_fma_f32 %0, %1, %2, %0" : "+v"(A1) : "v"(pk1[3]), "v"(wv3)); \
    asm("v_pk_fma_f32 %0, %1, %2, %0" : "+v"(A2) : "v"(pk2[3]), "v"(wv3)); \
    asm("v_pk_fma_f32 %0, %1, %2, %0" : "+v"(A0) : "v"(pk0[4]), "v"(v89)); \
    asm("v_pk_fma_f32 %0, %1, %2, %0" : "+v"(A1) : "v"(pk1[4]), "v"(v89)); \
    asm("v_pk_fma_f32 %0, %1, %2, %0" : "+v"(A2) : "v"(pk2[4]), "v"(v89)); \
    float a0 = A0.x + A0.y, a1 = A1.x + A1.y, a2 = A2.x + A2.y; \
    RED8(a0) RED8(a1) RED8(a2) \
    float w0, w1, w2; \
    UPD5(0, a0, w0) UPD5(1, a1, w1) UPD5(2, a2, w2) \
    wsel = (cc == 1) ? w1 : ((cc == 2) ? w2 : w0); \
    if (wvalid) (WNP)[widx] = wsel; }

    float* const wA = wbuf;
    float* const wB = wbuf + 8 * WROW;
    float wprev = 0.f, wsel = 0.f;
    unsigned int fvreg = 1u;
    for (int j2 = 0; j2 < ITERS / 2; ++j2) {
        ITERBODY(wA, wB)                  // it = 2*j2
        __syncthreads();
        ITERBODY(wB, wA)                  // it = 2*j2+1
        const bool chk = (j2 & 1) != 0;   // it%4==3
        int slot = 0;
        if (chk) {
            slot = (j2 >> 1) & 3;
            if (wvalid && fabsf(wsel - wprev) > EPS) flagsL[slot] = 1u;
            if (t == 0) flagsL[(slot + 2) & 3] = 0u;
            wprev = wsel;
        }
        __syncthreads();
        if (chk) {
            if (fvreg == 0u) break;       // stale-by-4-iters convergence info
            fvreg = flagsL[slot];          // non-blocking: consumed next check
        }
    }

    // ---- epilogue: x = Kinv*(At*w_final) - c  (final w always in wA) ----
    if (t < 64) {
        float acc = 0.f;
        for (int jo = 0; jo < 8; ++jo) {
#pragma unroll
            for (int ji = 0; ji < 10; ++ji)
                acc += amat[(jo * 10 + ji) * WAM + t] * wA[jo * WROW + ji];
        }
        fcol[t] = acc;
    }
    __syncthreads();
    float xp = 0.f;
#pragma unroll
    for (int c4 = 0; c4 < 4; ++c4) {
        float4 fv = *(const float4*)&fcol[qc * 16 + 4 * c4];
        xp += ar[4*c4]*fv.x + ar[4*c4+1]*fv.y + ar[4*c4+2]*fv.z + ar[4*c4+3]*fv.w;
    }
    xp = dpp_add(xp, 0xB1);
    xp = dpp_add(xp, 0x4E);
    if (qc == 0) out[(size_t)b * 64 + i] = xp - creg;
}

extern "C" void kernel_launch(void* const* d_in, const int* in_sizes, int n_in,
                              void* d_out, int out_size, void* d_ws, size_t ws_size,
                              hipStream_t stream) {
    const float* Q    = (const float*)d_in[0];
    const float* p    = (const float*)d_in[1];
    const float* A    = (const float*)d_in[2];
    const float* bvec = (const float*)d_in[3];
    const float* G    = (const float*)d_in[4];
    const float* h    = (const float*)d_in[5];
    float* out = (float*)d_out;
    admm_qp_kernel<<<1024, 256, 0, stream>>>(Q, p, A, bvec, G, h, out);
}

// Round 12
// 123.949 us; speedup vs baseline: 4.2226x; 1.0494x over previous
//
#include <hip/hip_runtime.h>

// Batched ADMM QP solver. One block (256 thr, 4 waves) per batch.
// Setup: K = Q + sigma*I + At*diag(rho)*A (rho_eq=100 on the 16 equality rows,
//   1 on inequalities -- OSQP-style; fixed point is rho-independent);
//   BLOCKED-2 register Gauss-Jordan; c = Kinv*p; d = -A*c;
//   P = A*Kinv*At in per-lane frags, packed vf2 for v_pk_fma_f32.
// Iterate <=800x (unrolled x2): over-relaxed ADMM alpha=1.6 in scaled-dual form:
//   Ax = P*wt + d; axr = a*Ax + (1-a)z; s = axr + yh; z' = med3(s,l,u);
//   yh' = s - z'; wt = rho_row*(z' - yh').
//   Lazy zero-critical-path convergence exit, per-row EPS scaled by rho_row.
// Epilogue: x = Kinv*(At*wt) - c.

#define ITERS 800
#define SIGMA 1e-6f
#define WAM  68     // amat row stride
#define MROW 96     // M half-buffer row stride
#define WROW 12     // padded w chunk stride (10 used + 2 pad)
#define EPS  1e-4f
#define ALPHA 1.6f
#define BETA  (-0.6f)   // 1 - ALPHA
#define RHO_E 100.0f    // penalty on equality rows (rows 0..15)

typedef float vf2 __attribute__((ext_vector_type(2)));
typedef float vf4 __attribute__((ext_vector_type(4)));

__device__ __forceinline__ float dpp_add(float x, const int ctrl) {
    int yi;
    switch (ctrl) {
        case 0xB1:  yi = __builtin_amdgcn_update_dpp(0, __float_as_int(x), 0xB1,  0xF, 0xF, true); break;
        case 0x4E:  yi = __builtin_amdgcn_update_dpp(0, __float_as_int(x), 0x4E,  0xF, 0xF, true); break;
        default:    yi = __builtin_amdgcn_update_dpp(0, __float_as_int(x), 0x141, 0xF, 0xF, true); break;
    }
    return x + __int_as_float(yi);
}

__global__ __launch_bounds__(256, 4)
void admm_qp_kernel(const float* __restrict__ Q, const float* __restrict__ p,
                    const float* __restrict__ A, const float* __restrict__ bvec,
                    const float* __restrict__ G, const float* __restrict__ h,
                    float* __restrict__ out)
{
    __shared__ float amat[80 * WAM];
    __shared__ float mh[32 * MROW];
    __shared__ float fcol[64];
    __shared__ float2 fcolB[64];       // raw (K[i][c0], K[i][c1]) for blocked GJ
    __shared__ float prow2[2 * 64];    // raw pivot rows p0, p1
    __shared__ float pvec[64];
    __shared__ float cvec[64];
    __shared__ float dvec[80];
    __shared__ __align__(16) float wbuf[2 * 8 * WROW];
    __shared__ unsigned int flagsL[4];

    const int b  = blockIdx.x;
    const int t  = threadIdx.x;
    const int i  = t >> 2, qc = t & 3;   // setup/epilogue mapping
    const int g  = t >> 3, cc = t & 7;   // iteration mapping

    const float* Ab = A + (size_t)b * 16 * 64;
    const float* Gb = G + (size_t)b * 64 * 64;
    const float* Qb = Q + (size_t)b * 64 * 64;

    // ---- stage Amat=[A;G], pvec; zero w buffers + flags ----
    for (int e = t; e < 80 * 16; e += 256) {
        int row = e >> 4, seg = e & 15;
        const float* src = (row < 16) ? (Ab + row * 64 + seg * 4)
                                      : (Gb + (row - 16) * 64 + seg * 4);
        *(float4*)&amat[row * WAM + seg * 4] = *(const float4*)src;
    }
    if (t < 64) pvec[t] = p[(size_t)b * 64 + t];
    if (t < 2 * 8 * WROW) wbuf[t] = 0.f;
    if (t < 4) flagsL[t] = 0u;
    __syncthreads();

    // ---- K = At*diag(rho)*A + Q + sigma*I ----
    float ar[16];
#pragma unroll
    for (int c = 0; c < 16; ++c) ar[c] = 0.f;
    for (int k = 0; k < 16; ++k) {          // equality rows: weight RHO_E
        const float* rowk = &amat[k * WAM];
        float av = rowk[i] * RHO_E;
#pragma unroll
        for (int c4 = 0; c4 < 4; ++c4) {
            float4 bv = *(const float4*)&rowk[qc * 16 + 4 * c4];
            ar[4*c4+0] += av * bv.x; ar[4*c4+1] += av * bv.y;
            ar[4*c4+2] += av * bv.z; ar[4*c4+3] += av * bv.w;
        }
    }
    for (int k = 16; k < 80; ++k) {         // inequality rows: weight 1
        const float* rowk = &amat[k * WAM];
        float av = rowk[i];
#pragma unroll
        for (int c4 = 0; c4 < 4; ++c4) {
            float4 bv = *(const float4*)&rowk[qc * 16 + 4 * c4];
            ar[4*c4+0] += av * bv.x; ar[4*c4+1] += av * bv.y;
            ar[4*c4+2] += av * bv.z; ar[4*c4+3] += av * bv.w;
        }
    }
#pragma unroll
    for (int c4 = 0; c4 < 4; ++c4) {
        float4 qv = *(const float4*)&Qb[i * 64 + qc * 16 + 4 * c4];
        ar[4*c4+0] += qv.x; ar[4*c4+1] += qv.y; ar[4*c4+2] += qv.z; ar[4*c4+3] += qv.w;
    }
    if ((i >> 4) == qc) ar[i & 15] += SIGMA;

    // ---- BLOCKED-2 register Gauss-Jordan (K SPD, no pivoting) ----
    for (int po = 0; po < 4; ++po) {
#pragma unroll
        for (int kbi = 0; kbi < 8; ++kbi) {
            const int p0 = po * 16 + 2 * kbi;
            const int p1 = p0 + 1;
            const int c0 = 2 * kbi;           // static
            const int c1 = c0 + 1;            // static
            if (qc == po) fcolB[i] = make_float2(ar[c0], ar[c1]);
            if (i == p0) {
#pragma unroll
                for (int c4 = 0; c4 < 4; ++c4)
                    *(float4*)&prow2[qc * 16 + 4 * c4] =
                        make_float4(ar[4*c4], ar[4*c4+1], ar[4*c4+2], ar[4*c4+3]);
            }
            if (i == p1) {
#pragma unroll
                for (int c4 = 0; c4 < 4; ++c4)
                    *(float4*)&prow2[64 + qc * 16 + 4 * c4] =
                        make_float4(ar[4*c4], ar[4*c4+1], ar[4*c4+2], ar[4*c4+3]);
            }
            __syncthreads();
            float2 fb = fcolB[i];
            float2 r0 = fcolB[p0];            // (a00, a01)
            float2 r1 = fcolB[p1];            // (a10, a11)
            float dinv = 1.0f / (r0.x * r1.y - r0.y * r1.x);
            float b00 =  r1.y * dinv, b01 = -r0.y * dinv;
            float b10 = -r1.x * dinv, b11 =  r0.x * dinv;
            float sp0[16], sp1[16];
#pragma unroll
            for (int c4 = 0; c4 < 4; ++c4) {
                float4 v0 = *(const float4*)&prow2[qc * 16 + 4 * c4];
                float4 v1 = *(const float4*)&prow2[64 + qc * 16 + 4 * c4];
                sp0[4*c4] = v0.x; sp0[4*c4+1] = v0.y; sp0[4*c4+2] = v0.z; sp0[4*c4+3] = v0.w;
                sp1[4*c4] = v1.x; sp1[4*c4+1] = v1.y; sp1[4*c4+2] = v1.z; sp1[4*c4+3] = v1.w;
            }
            if (i == p0) {
#pragma unroll
                for (int c = 0; c < 16; ++c) ar[c] = b00 * sp0[c] + b01 * sp1[c];
                if (qc == po) { ar[c0] = b00; ar[c1] = b01; }
            } else if (i == p1) {
#pragma unroll
                for (int c = 0; c < 16; ++c) ar[c] = b10 * sp0[c] + b11 * sp1[c];
                if (qc == po) { ar[c0] = b10; ar[c1] = b11; }
            } else {
                float g0 = fb.x * b00 + fb.y * b10;
                float g1 = fb.x * b01 + fb.y * b11;
#pragma unroll
                for (int c = 0; c < 16; ++c) ar[c] -= g0 * sp0[c] + g1 * sp1[c];
                if (qc == po) { ar[c0] = -g0; ar[c1] = -g1; }
            }
            __syncthreads();
        }
    }

    // ---- c = Kinv*p ----
    float creg;
    {
        float cacc = 0.f;
#pragma unroll
        for (int c4 = 0; c4 < 4; ++c4) {
            float4 pv4 = *(const float4*)&pvec[qc * 16 + 4 * c4];
            cacc += ar[4*c4]*pv4.x + ar[4*c4+1]*pv4.y + ar[4*c4+2]*pv4.z + ar[4*c4+3]*pv4.w;
        }
        cacc = dpp_add(cacc, 0xB1);
        cacc = dpp_add(cacc, 0x4E);
        creg = cacc;
        if (qc == 0) cvec[i] = cacc;
    }
    __syncthreads();

    // ---- d = -A*c ----
    if (t < 80) {
        float acc = 0.f;
#pragma unroll
        for (int k4 = 0; k4 < 16; ++k4) {
            float4 avv = *(const float4*)&amat[t * WAM + 4 * k4];
            float4 cv4 = *(const float4*)&cvec[4 * k4];
            acc += avv.x*cv4.x + avv.y*cv4.y + avv.z*cv4.z + avv.w*cv4.w;
        }
        dvec[t] = -acc;
    }
    __syncthreads();

    // ---- per-lane row state ----
    int rr[3];
    float dR[3], lR[3], uR[3], yR[3], zmR[3], rR[3];
#pragma unroll
    for (int j = 0; j < 3; ++j) {
        int r = 3 * g + j; if (r > 79) r = 79;
        rr[j] = r;
        dR[j] = dvec[r];
        if (r < 16) { float bb = bvec[(size_t)b * 16 + r]; lR[j] = bb; uR[j] = bb; rR[j] = RHO_E; }
        else        { lR[j] = -1e8f; uR[j] = h[(size_t)b * 64 + (r - 16)]; rR[j] = 1.0f; }
        yR[j] = 0.f; zmR[j] = 0.f;     // yh0 = 0, z0 = 0
    }

    // ---- P = A*(Kinv*At): two k-passes ----
    float pacc[3][10];
#pragma unroll
    for (int j = 0; j < 3; ++j)
#pragma unroll
        for (int c = 0; c < 10; ++c) pacc[j][c] = 0.f;

    for (int ps = 0; ps < 2; ++ps) {
        if ((t >> 7) == ps) {
            const int mrow = i & 31;
            for (int jo = 0; jo < 8; ++jo) {
#pragma unroll
                for (int ji = 0; ji < 10; ++ji) {
                    const int j = jo * 10 + ji;
                    const float* rj = &amat[j * WAM + qc * 16];
                    float acc = 0.f;
#pragma unroll
                    for (int c4 = 0; c4 < 4; ++c4) {
                        float4 av = *(const float4*)&rj[4 * c4];
                        acc += ar[4*c4]*av.x + ar[4*c4+1]*av.y + ar[4*c4+2]*av.z + ar[4*c4+3]*av.w;
                    }
                    acc = dpp_add(acc, 0xB1);
                    acc = dpp_add(acc, 0x4E);
                    if (qc == (ji & 3)) mh[mrow * MROW + jo * WROW + ji] = acc;
                }
            }
        }
        __syncthreads();
#pragma unroll 2
        for (int kb = 0; kb < 8; ++kb) {
            float a0[4], a1[4], a2[4];
            { float4 v = *(const float4*)&amat[rr[0]*WAM + ps*32 + kb*4]; a0[0]=v.x;a0[1]=v.y;a0[2]=v.z;a0[3]=v.w; }
            { float4 v = *(const float4*)&amat[rr[1]*WAM + ps*32 + kb*4]; a1[0]=v.x;a1[1]=v.y;a1[2]=v.z;a1[3]=v.w; }
            { float4 v = *(const float4*)&amat[rr[2]*WAM + ps*32 + kb*4]; a2[0]=v.x;a2[1]=v.y;a2[2]=v.z;a2[3]=v.w; }
#pragma unroll
            for (int kk = 0; kk < 4; ++kk) {
                const float* mrp = &mh[(kb * 4 + kk) * MROW + cc * WROW];
                float4 ma = *(const float4*)&mrp[0];
                float4 mb = *(const float4*)&mrp[4];
                float2 mc = *(const float2*)&mrp[8];
                float m[10] = {ma.x, ma.y, ma.z, ma.w, mb.x, mb.y, mb.z, mb.w, mc.x, mc.y};
#pragma unroll
                for (int c = 0; c < 10; ++c) {
                    pacc[0][c] += a0[kk] * m[c];
                    pacc[1][c] += a1[kk] * m[c];
                    pacc[2][c] += a2[kk] * m[c];
                }
            }
        }
        __syncthreads();
    }

    // ---- pack P fragments into vf2 pairs for v_pk_fma_f32 ----
    vf2 pk0[5], pk1[5], pk2[5];
#pragma unroll
    for (int c5 = 0; c5 < 5; ++c5) {
        pk0[c5] = (vf2){pacc[0][2*c5], pacc[0][2*c5+1]};
        pk1[c5] = (vf2){pacc[1][2*c5], pacc[1][2*c5+1]};
        pk2[c5] = (vf2){pacc[2][2*c5], pacc[2][2*c5+1]};
    }

    // ---- iterations (over-relaxed, diag-rho), unrolled x2 ----
    const int wrow  = 3 * g + cc;
    const bool wvalid = (cc < 3) && (wrow < 80);
    const int widx  = (wrow < 80) ? ((wrow / 10) * WROW + (wrow % 10)) : 0;
    const float rsel   = (cc == 1) ? rR[1] : ((cc == 2) ? rR[2] : rR[0]);
    const float epsSel = EPS * rsel;   // w-tilde scales with rho_row

#define RED8(a) a = dpp_add(a, 0xB1); a = dpp_add(a, 0x4E); a = dpp_add(a, 0x141);
#define UPD5(j, aj, wj) \
    { float ax = aj + dR[j]; \
      float axr = ALPHA * ax + zmR[j]; \
      float s = axr + yR[j]; \
      float z = __builtin_amdgcn_fmed3f(s, lR[j], uR[j]); \
      yR[j] = s - z; zmR[j] = BETA * z; wj = rR[j] * (z - yR[j]); }

#define ITERBODY(WCP, WNP) { \
    const float* wp = (WCP) + cc * WROW; \
    vf4 v04 = *(const vf4*)&wp[0]; \
    vf4 v47 = *(const vf4*)&wp[4]; \
    vf2 v89 = *(const vf2*)&wp[8]; \
    vf2 wv0 = __builtin_shufflevector(v04, v04, 0, 1); \
    vf2 wv1 = __builtin_shufflevector(v04, v04, 2, 3); \
    vf2 wv2 = __builtin_shufflevector(v47, v47, 0, 1); \
    vf2 wv3 = __builtin_shufflevector(v47, v47, 2, 3); \
    vf2 A0 = {0.f, 0.f}; vf2 A1 = {0.f, 0.f}; vf2 A2 = {0.f, 0.f}; \
    asm("v_pk_fma_f32 %0, %1, %2, %0" : "+v"(A0) : "v"(pk0[0]), "v"(wv0)); \
    asm("v_pk_fma_f32 %0, %1, %2, %0" : "+v"(A1) : "v"(pk1[0]), "v"(wv0)); \
    asm("v_pk_fma_f32 %0, %1, %2, %0" : "+v"(A2) : "v"(pk2[0]), "v"(wv0)); \
    asm("v_pk_fma_f32 %0, %1, %2, %0" : "+v"(A0) : "v"(pk0[1]), "v"(wv1)); \
    asm("v_pk_fma_f32 %0, %1, %2, %0" : "+v"(A1) : "v"(pk1[1]), "v"(wv1)); \
    asm("v_pk_fma_f32 %0, %1, %2, %0" : "+v"(A2) : "v"(pk2[1]), "v"(wv1)); \
    asm("v_pk_fma_f32 %0, %1, %2, %0" : "+v"(A0) : "v"(pk0[2]), "v"(wv2)); \
    asm("v_pk_fma_f32 %0, %1, %2, %0" : "+v"(A1) : "v"(pk1[2]), "v"(wv2)); \
    asm("v_pk_fma_f32 %0, %1, %2, %0" : "+v"(A2) : "v"(pk2[2]), "v"(wv2)); \
    asm("v_pk_fma_f32 %0, %1, %2, %0" : "+v"(A0) : "v"(pk0[3]), "v"(wv3)); \
    asm("v_pk_fma_f32 %0, %1, %2, %0" : "+v"(A1) : "v"(pk1[3]), "v"(wv3)); \
    asm("v_pk_fma_f32 %0, %1, %2, %0" : "+v"(A2) : "v"(pk2[3]), "v"(wv3)); \
    asm("v_pk_fma_f32 %0, %1, %2, %0" : "+v"(A0) : "v"(pk0[4]), "v"(v89)); \
    asm("v_pk_fma_f32 %0, %1, %2, %0" : "+v"(A1) : "v"(pk1[4]), "v"(v89)); \
    asm("v_pk_fma_f32 %0, %1, %2, %0" : "+v"(A2) : "v"(pk2[4]), "v"(v89)); \
    float a0 = A0.x + A0.y, a1 = A1.x + A1.y, a2 = A2.x + A2.y; \
    RED8(a0) RED8(a1) RED8(a2) \
    float w0, w1, w2; \
    UPD5(0, a0, w0) UPD5(1, a1, w1) UPD5(2, a2, w2) \
    wsel = (cc == 1) ? w1 : ((cc == 2) ? w2 : w0); \
    if (wvalid) (WNP)[widx] = wsel; }

    float* const wA = wbuf;
    float* const wB = wbuf + 8 * WROW;
    float wprev = 0.f, wsel = 0.f;
    unsigned int fvreg = 1u;
    for (int j2 = 0; j2 < ITERS / 2; ++j2) {
        ITERBODY(wA, wB)                  // it = 2*j2
        __syncthreads();
        ITERBODY(wB, wA)                  // it = 2*j2+1
        const bool chk = (j2 & 1) != 0;   // it%4==3
        int slot = 0;
        if (chk) {
            slot = (j2 >> 1) & 3;
            if (wvalid && fabsf(wsel - wprev) > epsSel) flagsL[slot] = 1u;
            if (t == 0) flagsL[(slot + 2) & 3] = 0u;
            wprev = wsel;
        }
        __syncthreads();
        if (chk) {
            if (fvreg == 0u) break;       // stale-by-4-iters convergence info
            fvreg = flagsL[slot];          // non-blocking: consumed next check
        }
    }

    // ---- epilogue: x = Kinv*(At*w_final) - c  (final w always in wA) ----
    if (t < 64) {
        float acc = 0.f;
        for (int jo = 0; jo < 8; ++jo) {
#pragma unroll
            for (int ji = 0; ji < 10; ++ji)
                acc += amat[(jo * 10 + ji) * WAM + t] * wA[jo * WROW + ji];
        }
        fcol[t] = acc;
    }
    __syncthreads();
    float xp = 0.f;
#pragma unroll
    for (int c4 = 0; c4 < 4; ++c4) {
        float4 fv = *(const float4*)&fcol[qc * 16 + 4 * c4];
        xp += ar[4*c4]*fv.x + ar[4*c4+1]*fv.y + ar[4*c4+2]*fv.z + ar[4*c4+3]*fv.w;
    }
    xp = dpp_add(xp, 0xB1);
    xp = dpp_add(xp, 0x4E);
    if (qc == 0) out[(size_t)b * 64 + i] = xp - creg;
}

extern "C" void kernel_launch(void* const* d_in, const int* in_sizes, int n_in,
                              void* d_out, int out_size, void* d_ws, size_t ws_size,
                              hipStream_t stream) {
    const float* Q    = (const float*)d_in[0];
    const float* p    = (const float*)d_in[1];
    const float* A    = (const float*)d_in[2];
    const float* bvec = (const float*)d_in[3];
    const float* G    = (const float*)d_in[4];
    const float* h    = (const float*)d_in[5];
    float* out = (float*)d_out;
    admm_qp_kernel<<<1024, 256, 0, stream>>>(Q, p, A, bvec, G, h, out);
}

// Round 13
// 109.463 us; speedup vs baseline: 4.7815x; 1.1323x over previous
//
#include <hip/hip_runtime.h>

// Batched ADMM QP solver. One block (256 thr, 4 waves) per batch.
// Setup: K = Q + sigma*I + At*diag(rho)*A (rho_eq=100, rho_ineq=1);
//   BLOCKED-2 register Gauss-Jordan; c = Kinv*p; d = -A*c;
//   P = A*Kinv*At in per-lane frags, packed vf2 for v_pk_fma_f32.
// Iterate <=800x (unrolled x2): over-relaxed ADMM alpha=1.8 scaled-dual form:
//   Ax = P*wt + d; axr = a*Ax + (1-a)z; s = axr + yh; z' = med3(s,l,u);
//   yh' = s - z'; wt = rho_row*(z' - yh').
// Round-13: alpha 1.6->1.8, convergence check every 2 iters (was 4),
//   EPS 1e-4 -> 2e-4. Zero-critical-path flag ring unchanged otherwise.
// Epilogue: x = Kinv*(At*wt) - c.

#define ITERS 800
#define SIGMA 1e-6f
#define WAM  68     // amat row stride
#define MROW 96     // M half-buffer row stride
#define WROW 12     // padded w chunk stride (10 used + 2 pad)
#define EPS  2e-4f
#define ALPHA 1.8f
#define BETA  (-0.8f)   // 1 - ALPHA
#define RHO_E 100.0f    // penalty on equality rows (rows 0..15)

typedef float vf2 __attribute__((ext_vector_type(2)));
typedef float vf4 __attribute__((ext_vector_type(4)));

__device__ __forceinline__ float dpp_add(float x, const int ctrl) {
    int yi;
    switch (ctrl) {
        case 0xB1:  yi = __builtin_amdgcn_update_dpp(0, __float_as_int(x), 0xB1,  0xF, 0xF, true); break;
        case 0x4E:  yi = __builtin_amdgcn_update_dpp(0, __float_as_int(x), 0x4E,  0xF, 0xF, true); break;
        default:    yi = __builtin_amdgcn_update_dpp(0, __float_as_int(x), 0x141, 0xF, 0xF, true); break;
    }
    return x + __int_as_float(yi);
}

__global__ __launch_bounds__(256, 4)
void admm_qp_kernel(const float* __restrict__ Q, const float* __restrict__ p,
                    const float* __restrict__ A, const float* __restrict__ bvec,
                    const float* __restrict__ G, const float* __restrict__ h,
                    float* __restrict__ out)
{
    __shared__ float amat[80 * WAM];
    __shared__ float mh[32 * MROW];
    __shared__ float fcol[64];
    __shared__ float2 fcolB[64];       // raw (K[i][c0], K[i][c1]) for blocked GJ
    __shared__ float prow2[2 * 64];    // raw pivot rows p0, p1
    __shared__ float pvec[64];
    __shared__ float cvec[64];
    __shared__ float dvec[80];
    __shared__ __align__(16) float wbuf[2 * 8 * WROW];
    __shared__ unsigned int flagsL[4];

    const int b  = blockIdx.x;
    const int t  = threadIdx.x;
    const int i  = t >> 2, qc = t & 3;   // setup/epilogue mapping
    const int g  = t >> 3, cc = t & 7;   // iteration mapping

    const float* Ab = A + (size_t)b * 16 * 64;
    const float* Gb = G + (size_t)b * 64 * 64;
    const float* Qb = Q + (size_t)b * 64 * 64;

    // ---- stage Amat=[A;G], pvec; zero w buffers + flags ----
    for (int e = t; e < 80 * 16; e += 256) {
        int row = e >> 4, seg = e & 15;
        const float* src = (row < 16) ? (Ab + row * 64 + seg * 4)
                                      : (Gb + (row - 16) * 64 + seg * 4);
        *(float4*)&amat[row * WAM + seg * 4] = *(const float4*)src;
    }
    if (t < 64) pvec[t] = p[(size_t)b * 64 + t];
    if (t < 2 * 8 * WROW) wbuf[t] = 0.f;
    if (t < 4) flagsL[t] = 0u;
    __syncthreads();

    // ---- K = At*diag(rho)*A + Q + sigma*I ----
    float ar[16];
#pragma unroll
    for (int c = 0; c < 16; ++c) ar[c] = 0.f;
    for (int k = 0; k < 16; ++k) {          // equality rows: weight RHO_E
        const float* rowk = &amat[k * WAM];
        float av = rowk[i] * RHO_E;
#pragma unroll
        for (int c4 = 0; c4 < 4; ++c4) {
            float4 bv = *(const float4*)&rowk[qc * 16 + 4 * c4];
            ar[4*c4+0] += av * bv.x; ar[4*c4+1] += av * bv.y;
            ar[4*c4+2] += av * bv.z; ar[4*c4+3] += av * bv.w;
        }
    }
    for (int k = 16; k < 80; ++k) {         // inequality rows: weight 1
        const float* rowk = &amat[k * WAM];
        float av = rowk[i];
#pragma unroll
        for (int c4 = 0; c4 < 4; ++c4) {
            float4 bv = *(const float4*)&rowk[qc * 16 + 4 * c4];
            ar[4*c4+0] += av * bv.x; ar[4*c4+1] += av * bv.y;
            ar[4*c4+2] += av * bv.z; ar[4*c4+3] += av * bv.w;
        }
    }
#pragma unroll
    for (int c4 = 0; c4 < 4; ++c4) {
        float4 qv = *(const float4*)&Qb[i * 64 + qc * 16 + 4 * c4];
        ar[4*c4+0] += qv.x; ar[4*c4+1] += qv.y; ar[4*c4+2] += qv.z; ar[4*c4+3] += qv.w;
    }
    if ((i >> 4) == qc) ar[i & 15] += SIGMA;

    // ---- BLOCKED-2 register Gauss-Jordan (K SPD, no pivoting) ----
    for (int po = 0; po < 4; ++po) {
#pragma unroll
        for (int kbi = 0; kbi < 8; ++kbi) {
            const int p0 = po * 16 + 2 * kbi;
            const int p1 = p0 + 1;
            const int c0 = 2 * kbi;           // static
            const int c1 = c0 + 1;            // static
            if (qc == po) fcolB[i] = make_float2(ar[c0], ar[c1]);
            if (i == p0) {
#pragma unroll
                for (int c4 = 0; c4 < 4; ++c4)
                    *(float4*)&prow2[qc * 16 + 4 * c4] =
                        make_float4(ar[4*c4], ar[4*c4+1], ar[4*c4+2], ar[4*c4+3]);
            }
            if (i == p1) {
#pragma unroll
                for (int c4 = 0; c4 < 4; ++c4)
                    *(float4*)&prow2[64 + qc * 16 + 4 * c4] =
                        make_float4(ar[4*c4], ar[4*c4+1], ar[4*c4+2], ar[4*c4+3]);
            }
            __syncthreads();
            float2 fb = fcolB[i];
            float2 r0 = fcolB[p0];            // (a00, a01)
            float2 r1 = fcolB[p1];            // (a10, a11)
            float dinv = 1.0f / (r0.x * r1.y - r0.y * r1.x);
            float b00 =  r1.y * dinv, b01 = -r0.y * dinv;
            float b10 = -r1.x * dinv, b11 =  r0.x * dinv;
            float sp0[16], sp1[16];
#pragma unroll
            for (int c4 = 0; c4 < 4; ++c4) {
                float4 v0 = *(const float4*)&prow2[qc * 16 + 4 * c4];
                float4 v1 = *(const float4*)&prow2[64 + qc * 16 + 4 * c4];
                sp0[4*c4] = v0.x; sp0[4*c4+1] = v0.y; sp0[4*c4+2] = v0.z; sp0[4*c4+3] = v0.w;
                sp1[4*c4] = v1.x; sp1[4*c4+1] = v1.y; sp1[4*c4+2] = v1.z; sp1[4*c4+3] = v1.w;
            }
            if (i == p0) {
#pragma unroll
                for (int c = 0; c < 16; ++c) ar[c] = b00 * sp0[c] + b01 * sp1[c];
                if (qc == po) { ar[c0] = b00; ar[c1] = b01; }
            } else if (i == p1) {
#pragma unroll
                for (int c = 0; c < 16; ++c) ar[c] = b10 * sp0[c] + b11 * sp1[c];
                if (qc == po) { ar[c0] = b10; ar[c1] = b11; }
            } else {
                float g0 = fb.x * b00 + fb.y * b10;
                float g1 = fb.x * b01 + fb.y * b11;
#pragma unroll
                for (int c = 0; c < 16; ++c) ar[c] -= g0 * sp0[c] + g1 * sp1[c];
                if (qc == po) { ar[c0] = -g0; ar[c1] = -g1; }
            }
            __syncthreads();
        }
    }

    // ---- c = Kinv*p ----
    float creg;
    {
        float cacc = 0.f;
#pragma unroll
        for (int c4 = 0; c4 < 4; ++c4) {
            float4 pv4 = *(const float4*)&pvec[qc * 16 + 4 * c4];
            cacc += ar[4*c4]*pv4.x + ar[4*c4+1]*pv4.y + ar[4*c4+2]*pv4.z + ar[4*c4+3]*pv4.w;
        }
        cacc = dpp_add(cacc, 0xB1);
        cacc = dpp_add(cacc, 0x4E);
        creg = cacc;
        if (qc == 0) cvec[i] = cacc;
    }
    __syncthreads();

    // ---- d = -A*c ----
    if (t < 80) {
        float acc = 0.f;
#pragma unroll
        for (int k4 = 0; k4 < 16; ++k4) {
            float4 avv = *(const float4*)&amat[t * WAM + 4 * k4];
            float4 cv4 = *(const float4*)&cvec[4 * k4];
            acc += avv.x*cv4.x + avv.y*cv4.y + avv.z*cv4.z + avv.w*cv4.w;
        }
        dvec[t] = -acc;
    }
    __syncthreads();

    // ---- per-lane row state ----
    int rr[3];
    float dR[3], lR[3], uR[3], yR[3], zmR[3], rR[3];
#pragma unroll
    for (int j = 0; j < 3; ++j) {
        int r = 3 * g + j; if (r > 79) r = 79;
        rr[j] = r;
        dR[j] = dvec[r];
        if (r < 16) { float bb = bvec[(size_t)b * 16 + r]; lR[j] = bb; uR[j] = bb; rR[j] = RHO_E; }
        else        { lR[j] = -1e8f; uR[j] = h[(size_t)b * 64 + (r - 16)]; rR[j] = 1.0f; }
        yR[j] = 0.f; zmR[j] = 0.f;     // yh0 = 0, z0 = 0
    }

    // ---- P = A*(Kinv*At): two k-passes ----
    float pacc[3][10];
#pragma unroll
    for (int j = 0; j < 3; ++j)
#pragma unroll
        for (int c = 0; c < 10; ++c) pacc[j][c] = 0.f;

    for (int ps = 0; ps < 2; ++ps) {
        if ((t >> 7) == ps) {
            const int mrow = i & 31;
            for (int jo = 0; jo < 8; ++jo) {
#pragma unroll
                for (int ji = 0; ji < 10; ++ji) {
                    const int j = jo * 10 + ji;
                    const float* rj = &amat[j * WAM + qc * 16];
                    float acc = 0.f;
#pragma unroll
                    for (int c4 = 0; c4 < 4; ++c4) {
                        float4 av = *(const float4*)&rj[4 * c4];
                        acc += ar[4*c4]*av.x + ar[4*c4+1]*av.y + ar[4*c4+2]*av.z + ar[4*c4+3]*av.w;
                    }
                    acc = dpp_add(acc, 0xB1);
                    acc = dpp_add(acc, 0x4E);
                    if (qc == (ji & 3)) mh[mrow * MROW + jo * WROW + ji] = acc;
                }
            }
        }
        __syncthreads();
#pragma unroll 2
        for (int kb = 0; kb < 8; ++kb) {
            float a0[4], a1[4], a2[4];
            { float4 v = *(const float4*)&amat[rr[0]*WAM + ps*32 + kb*4]; a0[0]=v.x;a0[1]=v.y;a0[2]=v.z;a0[3]=v.w; }
            { float4 v = *(const float4*)&amat[rr[1]*WAM + ps*32 + kb*4]; a1[0]=v.x;a1[1]=v.y;a1[2]=v.z;a1[3]=v.w; }
            { float4 v = *(const float4*)&amat[rr[2]*WAM + ps*32 + kb*4]; a2[0]=v.x;a2[1]=v.y;a2[2]=v.z;a2[3]=v.w; }
#pragma unroll
            for (int kk = 0; kk < 4; ++kk) {
                const float* mrp = &mh[(kb * 4 + kk) * MROW + cc * WROW];
                float4 ma = *(const float4*)&mrp[0];
                float4 mb = *(const float4*)&mrp[4];
                float2 mc = *(const float2*)&mrp[8];
                float m[10] = {ma.x, ma.y, ma.z, ma.w, mb.x, mb.y, mb.z, mb.w, mc.x, mc.y};
#pragma unroll
                for (int c = 0; c < 10; ++c) {
                    pacc[0][c] += a0[kk] * m[c];
                    pacc[1][c] += a1[kk] * m[c];
                    pacc[2][c] += a2[kk] * m[c];
                }
            }
        }
        __syncthreads();
    }

    // ---- pack P fragments into vf2 pairs for v_pk_fma_f32 ----
    vf2 pk0[5], pk1[5], pk2[5];
#pragma unroll
    for (int c5 = 0; c5 < 5; ++c5) {
        pk0[c5] = (vf2){pacc[0][2*c5], pacc[0][2*c5+1]};
        pk1[c5] = (vf2){pacc[1][2*c5], pacc[1][2*c5+1]};
        pk2[c5] = (vf2){pacc[2][2*c5], pacc[2][2*c5+1]};
    }

    // ---- iterations (over-relaxed, diag-rho), unrolled x2 ----
    const int wrow  = 3 * g + cc;
    const bool wvalid = (cc < 3) && (wrow < 80);
    const int widx  = (wrow < 80) ? ((wrow / 10) * WROW + (wrow % 10)) : 0;
    const float rsel   = (cc == 1) ? rR[1] : ((cc == 2) ? rR[2] : rR[0]);
    const float epsSel = EPS * rsel;   // w-tilde scales with rho_row

#define RED8(a) a = dpp_add(a, 0xB1); a = dpp_add(a, 0x4E); a = dpp_add(a, 0x141);
#define UPD5(j, aj, wj) \
    { float ax = aj + dR[j]; \
      float axr = ALPHA * ax + zmR[j]; \
      float s = axr + yR[j]; \
      float z = __builtin_amdgcn_fmed3f(s, lR[j], uR[j]); \
      yR[j] = s - z; zmR[j] = BETA * z; wj = rR[j] * (z - yR[j]); }

#define ITERBODY(WCP, WNP) { \
    const float* wp = (WCP) + cc * WROW; \
    vf4 v04 = *(const vf4*)&wp[0]; \
    vf4 v47 = *(const vf4*)&wp[4]; \
    vf2 v89 = *(const vf2*)&wp[8]; \
    vf2 wv0 = __builtin_shufflevector(v04, v04, 0, 1); \
    vf2 wv1 = __builtin_shufflevector(v04, v04, 2, 3); \
    vf2 wv2 = __builtin_shufflevector(v47, v47, 0, 1); \
    vf2 wv3 = __builtin_shufflevector(v47, v47, 2, 3); \
    vf2 A0 = {0.f, 0.f}; vf2 A1 = {0.f, 0.f}; vf2 A2 = {0.f, 0.f}; \
    asm("v_pk_fma_f32 %0, %1, %2, %0" : "+v"(A0) : "v"(pk0[0]), "v"(wv0)); \
    asm("v_pk_fma_f32 %0, %1, %2, %0" : "+v"(A1) : "v"(pk1[0]), "v"(wv0)); \
    asm("v_pk_fma_f32 %0, %1, %2, %0" : "+v"(A2) : "v"(pk2[0]), "v"(wv0)); \
    asm("v_pk_fma_f32 %0, %1, %2, %0" : "+v"(A0) : "v"(pk0[1]), "v"(wv1)); \
    asm("v_pk_fma_f32 %0, %1, %2, %0" : "+v"(A1) : "v"(pk1[1]), "v"(wv1)); \
    asm("v_pk_fma_f32 %0, %1, %2, %0" : "+v"(A2) : "v"(pk2[1]), "v"(wv1)); \
    asm("v_pk_fma_f32 %0, %1, %2, %0" : "+v"(A0) : "v"(pk0[2]), "v"(wv2)); \
    asm("v_pk_fma_f32 %0, %1, %2, %0" : "+v"(A1) : "v"(pk1[2]), "v"(wv2)); \
    asm("v_pk_fma_f32 %0, %1, %2, %0" : "+v"(A2) : "v"(pk2[2]), "v"(wv2)); \
    asm("v_pk_fma_f32 %0, %1, %2, %0" : "+v"(A0) : "v"(pk0[3]), "v"(wv3)); \
    asm("v_pk_fma_f32 %0, %1, %2, %0" : "+v"(A1) : "v"(pk1[3]), "v"(wv3)); \
    asm("v_pk_fma_f32 %0, %1, %2, %0" : "+v"(A2) : "v"(pk2[3]), "v"(wv3)); \
    asm("v_pk_fma_f32 %0, %1, %2, %0" : "+v"(A0) : "v"(pk0[4]), "v"(v89)); \
    asm("v_pk_fma_f32 %0, %1, %2, %0" : "+v"(A1) : "v"(pk1[4]), "v"(v89)); \
    asm("v_pk_fma_f32 %0, %1, %2, %0" : "+v"(A2) : "v"(pk2[4]), "v"(v89)); \
    float a0 = A0.x + A0.y, a1 = A1.x + A1.y, a2 = A2.x + A2.y; \
    RED8(a0) RED8(a1) RED8(a2) \
    float w0, w1, w2; \
    UPD5(0, a0, w0) UPD5(1, a1, w1) UPD5(2, a2, w2) \
    wsel = (cc == 1) ? w1 : ((cc == 2) ? w2 : w0); \
    if (wvalid) (WNP)[widx] = wsel; }

    float* const wA = wbuf;
    float* const wB = wbuf + 8 * WROW;
    float wprev = 0.f, wsel = 0.f;
    unsigned int fvreg = 1u;
    for (int j2 = 0; j2 < ITERS / 2; ++j2) {
        ITERBODY(wA, wB)                  // it = 2*j2
        __syncthreads();
        ITERBODY(wB, wA)                  // it = 2*j2+1
        const int slot = j2 & 3;          // check EVERY 2 iterations
        if (wvalid && fabsf(wsel - wprev) > epsSel) flagsL[slot] = 1u;
        if (t == 0) flagsL[(slot + 2) & 3] = 0u;   // zero-ahead, 2 checks apart
        wprev = wsel;
        __syncthreads();
        if (fvreg == 0u) break;           // stale-by-2-iters convergence info
        fvreg = flagsL[slot];             // non-blocking: consumed next check
    }

    // ---- epilogue: x = Kinv*(At*w_final) - c  (final w always in wA) ----
    if (t < 64) {
        float acc = 0.f;
        for (int jo = 0; jo < 8; ++jo) {
#pragma unroll
            for (int ji = 0; ji < 10; ++ji)
                acc += amat[(jo * 10 + ji) * WAM + t] * wA[jo * WROW + ji];
        }
        fcol[t] = acc;
    }
    __syncthreads();
    float xp = 0.f;
#pragma unroll
    for (int c4 = 0; c4 < 4; ++c4) {
        float4 fv = *(const float4*)&fcol[qc * 16 + 4 * c4];
        xp += ar[4*c4]*fv.x + ar[4*c4+1]*fv.y + ar[4*c4+2]*fv.z + ar[4*c4+3]*fv.w;
    }
    xp = dpp_add(xp, 0xB1);
    xp = dpp_add(xp, 0x4E);
    if (qc == 0) out[(size_t)b * 64 + i] = xp - creg;
}

extern "C" void kernel_launch(void* const* d_in, const int* in_sizes, int n_in,
                              void* d_out, int out_size, void* d_ws, size_t ws_size,
                              hipStream_t stream) {
    const float* Q    = (const float*)d_in[0];
    const float* p    = (const float*)d_in[1];
    const float* A    = (const float*)d_in[2];
    const float* bvec = (const float*)d_in[3];
    const float* G    = (const float*)d_in[4];
    const float* h    = (const float*)d_in[5];
    float* out = (float*)d_out;
    admm_qp_kernel<<<1024, 256, 0, stream>>>(Q, p, A, bvec, G, h, out);
}

// Round 14
// 107.103 us; speedup vs baseline: 4.8868x; 1.0220x over previous
//
#include <hip/hip_runtime.h>

// Batched ADMM QP solver. One block (256 thr, 4 waves) per batch.
// Setup: K = Q + sigma*I + At*diag(rho)*A (rho_eq=100, rho_ineq=1);
//   BLOCKED-2 register Gauss-Jordan; c = Kinv*p; d = -A*c;
//   P = A*Kinv*At in per-lane frags, packed vf2 for v_pk_fma_f32.
// Iterate <=800x (unrolled x2): over-relaxed ADMM alpha=1.8 scaled-dual form:
//   Ax = P*wt + d; axr = a*Ax + (1-a)z; s = axr + yh; z' = med3(s,l,u);
//   yh' = s - z'; wt = rho_row*(z' - yh').
// Round-14: WARM START -- z0 = med3(d, l, u) (d = A*x_unconstrained), y0 = 0,
//   w0 = rho*z0, zm0 = (1-alpha)*z0. Same fixed point, shorter trajectory.
//   Everything else identical to round 13.
// Epilogue: x = Kinv*(At*wt) - c.

#define ITERS 800
#define SIGMA 1e-6f
#define WAM  68     // amat row stride
#define MROW 96     // M half-buffer row stride
#define WROW 12     // padded w chunk stride (10 used + 2 pad)
#define EPS  2e-4f
#define ALPHA 1.8f
#define BETA  (-0.8f)   // 1 - ALPHA
#define RHO_E 100.0f    // penalty on equality rows (rows 0..15)

typedef float vf2 __attribute__((ext_vector_type(2)));
typedef float vf4 __attribute__((ext_vector_type(4)));

__device__ __forceinline__ float dpp_add(float x, const int ctrl) {
    int yi;
    switch (ctrl) {
        case 0xB1:  yi = __builtin_amdgcn_update_dpp(0, __float_as_int(x), 0xB1,  0xF, 0xF, true); break;
        case 0x4E:  yi = __builtin_amdgcn_update_dpp(0, __float_as_int(x), 0x4E,  0xF, 0xF, true); break;
        default:    yi = __builtin_amdgcn_update_dpp(0, __float_as_int(x), 0x141, 0xF, 0xF, true); break;
    }
    return x + __int_as_float(yi);
}

__global__ __launch_bounds__(256, 4)
void admm_qp_kernel(const float* __restrict__ Q, const float* __restrict__ p,
                    const float* __restrict__ A, const float* __restrict__ bvec,
                    const float* __restrict__ G, const float* __restrict__ h,
                    float* __restrict__ out)
{
    __shared__ float amat[80 * WAM];
    __shared__ float mh[32 * MROW];
    __shared__ float fcol[64];
    __shared__ float2 fcolB[64];       // raw (K[i][c0], K[i][c1]) for blocked GJ
    __shared__ float prow2[2 * 64];    // raw pivot rows p0, p1
    __shared__ float pvec[64];
    __shared__ float cvec[64];
    __shared__ float dvec[80];
    __shared__ __align__(16) float wbuf[2 * 8 * WROW];
    __shared__ unsigned int flagsL[4];

    const int b  = blockIdx.x;
    const int t  = threadIdx.x;
    const int i  = t >> 2, qc = t & 3;   // setup/epilogue mapping
    const int g  = t >> 3, cc = t & 7;   // iteration mapping

    const float* Ab = A + (size_t)b * 16 * 64;
    const float* Gb = G + (size_t)b * 64 * 64;
    const float* Qb = Q + (size_t)b * 64 * 64;

    // ---- stage Amat=[A;G], pvec; zero w buffers + flags ----
    for (int e = t; e < 80 * 16; e += 256) {
        int row = e >> 4, seg = e & 15;
        const float* src = (row < 16) ? (Ab + row * 64 + seg * 4)
                                      : (Gb + (row - 16) * 64 + seg * 4);
        *(float4*)&amat[row * WAM + seg * 4] = *(const float4*)src;
    }
    if (t < 64) pvec[t] = p[(size_t)b * 64 + t];
    if (t < 2 * 8 * WROW) wbuf[t] = 0.f;
    if (t < 4) flagsL[t] = 0u;
    __syncthreads();

    // ---- K = At*diag(rho)*A + Q + sigma*I ----
    float ar[16];
#pragma unroll
    for (int c = 0; c < 16; ++c) ar[c] = 0.f;
    for (int k = 0; k < 16; ++k) {          // equality rows: weight RHO_E
        const float* rowk = &amat[k * WAM];
        float av = rowk[i] * RHO_E;
#pragma unroll
        for (int c4 = 0; c4 < 4; ++c4) {
            float4 bv = *(const float4*)&rowk[qc * 16 + 4 * c4];
            ar[4*c4+0] += av * bv.x; ar[4*c4+1] += av * bv.y;
            ar[4*c4+2] += av * bv.z; ar[4*c4+3] += av * bv.w;
        }
    }
    for (int k = 16; k < 80; ++k) {         // inequality rows: weight 1
        const float* rowk = &amat[k * WAM];
        float av = rowk[i];
#pragma unroll
        for (int c4 = 0; c4 < 4; ++c4) {
            float4 bv = *(const float4*)&rowk[qc * 16 + 4 * c4];
            ar[4*c4+0] += av * bv.x; ar[4*c4+1] += av * bv.y;
            ar[4*c4+2] += av * bv.z; ar[4*c4+3] += av * bv.w;
        }
    }
#pragma unroll
    for (int c4 = 0; c4 < 4; ++c4) {
        float4 qv = *(const float4*)&Qb[i * 64 + qc * 16 + 4 * c4];
        ar[4*c4+0] += qv.x; ar[4*c4+1] += qv.y; ar[4*c4+2] += qv.z; ar[4*c4+3] += qv.w;
    }
    if ((i >> 4) == qc) ar[i & 15] += SIGMA;

    // ---- BLOCKED-2 register Gauss-Jordan (K SPD, no pivoting) ----
    for (int po = 0; po < 4; ++po) {
#pragma unroll
        for (int kbi = 0; kbi < 8; ++kbi) {
            const int p0 = po * 16 + 2 * kbi;
            const int p1 = p0 + 1;
            const int c0 = 2 * kbi;           // static
            const int c1 = c0 + 1;            // static
            if (qc == po) fcolB[i] = make_float2(ar[c0], ar[c1]);
            if (i == p0) {
#pragma unroll
                for (int c4 = 0; c4 < 4; ++c4)
                    *(float4*)&prow2[qc * 16 + 4 * c4] =
                        make_float4(ar[4*c4], ar[4*c4+1], ar[4*c4+2], ar[4*c4+3]);
            }
            if (i == p1) {
#pragma unroll
                for (int c4 = 0; c4 < 4; ++c4)
                    *(float4*)&prow2[64 + qc * 16 + 4 * c4] =
                        make_float4(ar[4*c4], ar[4*c4+1], ar[4*c4+2], ar[4*c4+3]);
            }
            __syncthreads();
            float2 fb = fcolB[i];
            float2 r0 = fcolB[p0];            // (a00, a01)
            float2 r1 = fcolB[p1];            // (a10, a11)
            float dinv = 1.0f / (r0.x * r1.y - r0.y * r1.x);
            float b00 =  r1.y * dinv, b01 = -r0.y * dinv;
            float b10 = -r1.x * dinv, b11 =  r0.x * dinv;
            float sp0[16], sp1[16];
#pragma unroll
            for (int c4 = 0; c4 < 4; ++c4) {
                float4 v0 = *(const float4*)&prow2[qc * 16 + 4 * c4];
                float4 v1 = *(const float4*)&prow2[64 + qc * 16 + 4 * c4];
                sp0[4*c4] = v0.x; sp0[4*c4+1] = v0.y; sp0[4*c4+2] = v0.z; sp0[4*c4+3] = v0.w;
                sp1[4*c4] = v1.x; sp1[4*c4+1] = v1.y; sp1[4*c4+2] = v1.z; sp1[4*c4+3] = v1.w;
            }
            if (i == p0) {
#pragma unroll
                for (int c = 0; c < 16; ++c) ar[c] = b00 * sp0[c] + b01 * sp1[c];
                if (qc == po) { ar[c0] = b00; ar[c1] = b01; }
            } else if (i == p1) {
#pragma unroll
                for (int c = 0; c < 16; ++c) ar[c] = b10 * sp0[c] + b11 * sp1[c];
                if (qc == po) { ar[c0] = b10; ar[c1] = b11; }
            } else {
                float g0 = fb.x * b00 + fb.y * b10;
                float g1 = fb.x * b01 + fb.y * b11;
#pragma unroll
                for (int c = 0; c < 16; ++c) ar[c] -= g0 * sp0[c] + g1 * sp1[c];
                if (qc == po) { ar[c0] = -g0; ar[c1] = -g1; }
            }
            __syncthreads();
        }
    }

    // ---- c = Kinv*p ----
    float creg;
    {
        float cacc = 0.f;
#pragma unroll
        for (int c4 = 0; c4 < 4; ++c4) {
            float4 pv4 = *(const float4*)&pvec[qc * 16 + 4 * c4];
            cacc += ar[4*c4]*pv4.x + ar[4*c4+1]*pv4.y + ar[4*c4+2]*pv4.z + ar[4*c4+3]*pv4.w;
        }
        cacc = dpp_add(cacc, 0xB1);
        cacc = dpp_add(cacc, 0x4E);
        creg = cacc;
        if (qc == 0) cvec[i] = cacc;
    }
    __syncthreads();

    // ---- d = -A*c ----
    if (t < 80) {
        float acc = 0.f;
#pragma unroll
        for (int k4 = 0; k4 < 16; ++k4) {
            float4 avv = *(const float4*)&amat[t * WAM + 4 * k4];
            float4 cv4 = *(const float4*)&cvec[4 * k4];
            acc += avv.x*cv4.x + avv.y*cv4.y + avv.z*cv4.z + avv.w*cv4.w;
        }
        dvec[t] = -acc;
    }
    __syncthreads();

    // ---- per-lane row state + WARM START z0 = med3(d, l, u) ----
    int rr[3];
    float dR[3], lR[3], uR[3], yR[3], zmR[3], rR[3], w0R[3];
#pragma unroll
    for (int j = 0; j < 3; ++j) {
        int r = 3 * g + j; if (r > 79) r = 79;
        rr[j] = r;
        dR[j] = dvec[r];
        if (r < 16) { float bb = bvec[(size_t)b * 16 + r]; lR[j] = bb; uR[j] = bb; rR[j] = RHO_E; }
        else        { lR[j] = -1e8f; uR[j] = h[(size_t)b * 64 + (r - 16)]; rR[j] = 1.0f; }
        float z0 = __builtin_amdgcn_fmed3f(dR[j], lR[j], uR[j]);
        yR[j] = 0.f; zmR[j] = BETA * z0; w0R[j] = rR[j] * z0;
    }

    // ---- P = A*(Kinv*At): two k-passes ----
    float pacc[3][10];
#pragma unroll
    for (int j = 0; j < 3; ++j)
#pragma unroll
        for (int c = 0; c < 10; ++c) pacc[j][c] = 0.f;

    for (int ps = 0; ps < 2; ++ps) {
        if ((t >> 7) == ps) {
            const int mrow = i & 31;
            for (int jo = 0; jo < 8; ++jo) {
#pragma unroll
                for (int ji = 0; ji < 10; ++ji) {
                    const int j = jo * 10 + ji;
                    const float* rj = &amat[j * WAM + qc * 16];
                    float acc = 0.f;
#pragma unroll
                    for (int c4 = 0; c4 < 4; ++c4) {
                        float4 av = *(const float4*)&rj[4 * c4];
                        acc += ar[4*c4]*av.x + ar[4*c4+1]*av.y + ar[4*c4+2]*av.z + ar[4*c4+3]*av.w;
                    }
                    acc = dpp_add(acc, 0xB1);
                    acc = dpp_add(acc, 0x4E);
                    if (qc == (ji & 3)) mh[mrow * MROW + jo * WROW + ji] = acc;
                }
            }
        }
        __syncthreads();
#pragma unroll 2
        for (int kb = 0; kb < 8; ++kb) {
            float a0[4], a1[4], a2[4];
            { float4 v = *(const float4*)&amat[rr[0]*WAM + ps*32 + kb*4]; a0[0]=v.x;a0[1]=v.y;a0[2]=v.z;a0[3]=v.w; }
            { float4 v = *(const float4*)&amat[rr[1]*WAM + ps*32 + kb*4]; a1[0]=v.x;a1[1]=v.y;a1[2]=v.z;a1[3]=v.w; }
            { float4 v = *(const float4*)&amat[rr[2]*WAM + ps*32 + kb*4]; a2[0]=v.x;a2[1]=v.y;a2[2]=v.z;a2[3]=v.w; }
#pragma unroll
            for (int kk = 0; kk < 4; ++kk) {
                const float* mrp = &mh[(kb * 4 + kk) * MROW + cc * WROW];
                float4 ma = *(const float4*)&mrp[0];
                float4 mb = *(const float4*)&mrp[4];
                float2 mc = *(const float2*)&mrp[8];
                float m[10] = {ma.x, ma.y, ma.z, ma.w, mb.x, mb.y, mb.z, mb.w, mc.x, mc.y};
#pragma unroll
                for (int c = 0; c < 10; ++c) {
                    pacc[0][c] += a0[kk] * m[c];
                    pacc[1][c] += a1[kk] * m[c];
                    pacc[2][c] += a2[kk] * m[c];
                }
            }
        }
        __syncthreads();
    }

    // ---- pack P fragments into vf2 pairs for v_pk_fma_f32 ----
    vf2 pk0[5], pk1[5], pk2[5];
#pragma unroll
    for (int c5 = 0; c5 < 5; ++c5) {
        pk0[c5] = (vf2){pacc[0][2*c5], pacc[0][2*c5+1]};
        pk1[c5] = (vf2){pacc[1][2*c5], pacc[1][2*c5+1]};
        pk2[c5] = (vf2){pacc[2][2*c5], pacc[2][2*c5+1]};
    }

    // ---- iterations (over-relaxed, diag-rho, warm-started), unrolled x2 ----
    const int wrow  = 3 * g + cc;
    const bool wvalid = (cc < 3) && (wrow < 80);
    const int widx  = (wrow < 80) ? ((wrow / 10) * WROW + (wrow % 10)) : 0;
    const float rsel   = (cc == 1) ? rR[1] : ((cc == 2) ? rR[2] : rR[0]);
    const float epsSel = EPS * rsel;   // w-tilde scales with rho_row

    // warm-start w0 into wA
    {
        float w0sel = (cc == 1) ? w0R[1] : ((cc == 2) ? w0R[2] : w0R[0]);
        if (wvalid) wbuf[widx] = w0sel;
    }
    __syncthreads();

#define RED8(a) a = dpp_add(a, 0xB1); a = dpp_add(a, 0x4E); a = dpp_add(a, 0x141);
#define UPD5(j, aj, wj) \
    { float ax = aj + dR[j]; \
      float axr = ALPHA * ax + zmR[j]; \
      float s = axr + yR[j]; \
      float z = __builtin_amdgcn_fmed3f(s, lR[j], uR[j]); \
      yR[j] = s - z; zmR[j] = BETA * z; wj = rR[j] * (z - yR[j]); }

#define ITERBODY(WCP, WNP) { \
    const float* wp = (WCP) + cc * WROW; \
    vf4 v04 = *(const vf4*)&wp[0]; \
    vf4 v47 = *(const vf4*)&wp[4]; \
    vf2 v89 = *(const vf2*)&wp[8]; \
    vf2 wv0 = __builtin_shufflevector(v04, v04, 0, 1); \
    vf2 wv1 = __builtin_shufflevector(v04, v04, 2, 3); \
    vf2 wv2 = __builtin_shufflevector(v47, v47, 0, 1); \
    vf2 wv3 = __builtin_shufflevector(v47, v47, 2, 3); \
    vf2 A0 = {0.f, 0.f}; vf2 A1 = {0.f, 0.f}; vf2 A2 = {0.f, 0.f}; \
    asm("v_pk_fma_f32 %0, %1, %2, %0" : "+v"(A0) : "v"(pk0[0]), "v"(wv0)); \
    asm("v_pk_fma_f32 %0, %1, %2, %0" : "+v"(A1) : "v"(pk1[0]), "v"(wv0)); \
    asm("v_pk_fma_f32 %0, %1, %2, %0" : "+v"(A2) : "v"(pk2[0]), "v"(wv0)); \
    asm("v_pk_fma_f32 %0, %1, %2, %0" : "+v"(A0) : "v"(pk0[1]), "v"(wv1)); \
    asm("v_pk_fma_f32 %0, %1, %2, %0" : "+v"(A1) : "v"(pk1[1]), "v"(wv1)); \
    asm("v_pk_fma_f32 %0, %1, %2, %0" : "+v"(A2) : "v"(pk2[1]), "v"(wv1)); \
    asm("v_pk_fma_f32 %0, %1, %2, %0" : "+v"(A0) : "v"(pk0[2]), "v"(wv2)); \
    asm("v_pk_fma_f32 %0, %1, %2, %0" : "+v"(A1) : "v"(pk1[2]), "v"(wv2)); \
    asm("v_pk_fma_f32 %0, %1, %2, %0" : "+v"(A2) : "v"(pk2[2]), "v"(wv2)); \
    asm("v_pk_fma_f32 %0, %1, %2, %0" : "+v"(A0) : "v"(pk0[3]), "v"(wv3)); \
    asm("v_pk_fma_f32 %0, %1, %2, %0" : "+v"(A1) : "v"(pk1[3]), "v"(wv3)); \
    asm("v_pk_fma_f32 %0, %1, %2, %0" : "+v"(A2) : "v"(pk2[3]), "v"(wv3)); \
    asm("v_pk_fma_f32 %0, %1, %2, %0" : "+v"(A0) : "v"(pk0[4]), "v"(v89)); \
    asm("v_pk_fma_f32 %0, %1, %2, %0" : "+v"(A1) : "v"(pk1[4]), "v"(v89)); \
    asm("v_pk_fma_f32 %0, %1, %2, %0" : "+v"(A2) : "v"(pk2[4]), "v"(v89)); \
    float a0 = A0.x + A0.y, a1 = A1.x + A1.y, a2 = A2.x + A2.y; \
    RED8(a0) RED8(a1) RED8(a2) \
    float w0, w1, w2; \
    UPD5(0, a0, w0) UPD5(1, a1, w1) UPD5(2, a2, w2) \
    wsel = (cc == 1) ? w1 : ((cc == 2) ? w2 : w0); \
    if (wvalid) (WNP)[widx] = wsel; }

    float* const wA = wbuf;
    float* const wB = wbuf + 8 * WROW;
    float wprev = 0.f, wsel = 0.f;
    unsigned int fvreg = 1u;
    for (int j2 = 0; j2 < ITERS / 2; ++j2) {
        ITERBODY(wA, wB)                  // it = 2*j2
        __syncthreads();
        ITERBODY(wB, wA)                  // it = 2*j2+1
        const int slot = j2 & 3;          // check EVERY 2 iterations
        if (wvalid && fabsf(wsel - wprev) > epsSel) flagsL[slot] = 1u;
        if (t == 0) flagsL[(slot + 2) & 3] = 0u;   // zero-ahead, 2 checks apart
        wprev = wsel;
        __syncthreads();
        if (fvreg == 0u) break;           // stale-by-2-iters convergence info
        fvreg = flagsL[slot];             // non-blocking: consumed next check
    }

    // ---- epilogue: x = Kinv*(At*w_final) - c  (final w always in wA) ----
    if (t < 64) {
        float acc = 0.f;
        for (int jo = 0; jo < 8; ++jo) {
#pragma unroll
            for (int ji = 0; ji < 10; ++ji)
                acc += amat[(jo * 10 + ji) * WAM + t] * wA[jo * WROW + ji];
        }
        fcol[t] = acc;
    }
    __syncthreads();
    float xp = 0.f;
#pragma unroll
    for (int c4 = 0; c4 < 4; ++c4) {
        float4 fv = *(const float4*)&fcol[qc * 16 + 4 * c4];
        xp += ar[4*c4]*fv.x + ar[4*c4+1]*fv.y + ar[4*c4+2]*fv.z + ar[4*c4+3]*fv.w;
    }
    xp = dpp_add(xp, 0xB1);
    xp = dpp_add(xp, 0x4E);
    if (qc == 0) out[(size_t)b * 64 + i] = xp - creg;
}

extern "C" void kernel_launch(void* const* d_in, const int* in_sizes, int n_in,
                              void* d_out, int out_size, void* d_ws, size_t ws_size,
                              hipStream_t stream) {
    const float* Q    = (const float*)d_in[0];
    const float* p    = (const float*)d_in[1];
    const float* A    = (const float*)d_in[2];
    const float* bvec = (const float*)d_in[3];
    const float* G    = (const float*)d_in[4];
    const float* h    = (const float*)d_in[5];
    float* out = (float*)d_out;
    admm_qp_kernel<<<1024, 256, 0, stream>>>(Q, p, A, bvec, G, h, out);
}